// Round 10
// baseline (735.861 us; speedup 1.0000x reference)
//
#include <hip/hip_runtime.h>

#define DF 128
#define RB 512            // nodes per bucket (power of two)
#define RB_SHIFT 9
#define NB_MAX 256        // supports n <= 131072
#define CHUNK 8192        // edges per binning block

// ---------------- CSR build (bucketed, coalesced) ----------------

__global__ void k_bhist(const int* __restrict__ dst, int* __restrict__ bcnt, int e){
  __shared__ int h[NB_MAX];
  int t = threadIdx.x;
  h[t] = 0;
  __syncthreads();
  int base = blockIdx.x*CHUNK;
  for(int k=0;k<CHUNK/256;k++){
    int i = base + t + k*256;
    if(i<e) atomicAdd(&h[dst[i]>>RB_SHIFT], 1);
  }
  __syncthreads();
  if(h[t]) atomicAdd(&bcnt[t], h[t]);
}

__global__ void k_bscan(const int* __restrict__ bcnt, int* __restrict__ bbase,
                        int* __restrict__ bcur, int e){
  __shared__ int sh[NB_MAX];
  int t = threadIdx.x;
  int c = bcnt[t];
  sh[t] = c;
  __syncthreads();
  for(int off=1; off<256; off<<=1){
    int v = (t>=off)? sh[t-off]:0;
    __syncthreads();
    sh[t]+=v;
    __syncthreads();
  }
  int excl = sh[t]-c;
  bbase[t]=excl; bcur[t]=excl;
  if(t==255) bbase[256]=sh[255];   // == e
}

__launch_bounds__(256)
__global__ void k_binscatter(const int* __restrict__ src, const int* __restrict__ dst,
                             int* __restrict__ bcur, int2* __restrict__ binned, int e){
  __shared__ int h[NB_MAX];
  __shared__ int lexcl[NB_MAX];
  __shared__ int lcur[NB_MAX];
  __shared__ int gbase[NB_MAX];
  __shared__ int2 pairs[CHUNK];
  int t = threadIdx.x;
  int c0 = blockIdx.x*CHUNK;
  int cc = min(CHUNK, e - c0);
  h[t]=0;
  __syncthreads();
  for(int k=0;k<CHUNK/256;k++){
    int i = t + k*256;
    if(i<cc) atomicAdd(&h[dst[c0+i]>>RB_SHIFT], 1);
  }
  __syncthreads();
  int hc = h[t];
  lexcl[t]=hc;
  __syncthreads();
  for(int off=1; off<256; off<<=1){
    int v = (t>=off)? lexcl[t-off]:0;
    __syncthreads();
    lexcl[t]+=v;
    __syncthreads();
  }
  int incl = lexcl[t];
  lexcl[t] = incl - hc;
  lcur[t]  = incl - hc;
  gbase[t] = hc ? atomicAdd(&bcur[t], hc) : 0;
  __syncthreads();
  for(int k=0;k<CHUNK/256;k++){
    int i = t + k*256;
    if(i<cc){
      int d = dst[c0+i], s = src[c0+i];
      int lp = atomicAdd(&lcur[d>>RB_SHIFT], 1);
      pairs[lp] = make_int2(d, s);
    }
  }
  __syncthreads();
  for(int k=0;k<CHUNK/256;k++){
    int p = t + k*256;
    if(p<cc){
      int2 pr = pairs[p];
      int b = pr.x>>RB_SHIFT;
      binned[gbase[b] + (p - lexcl[b])] = pr;
    }
  }
}

__launch_bounds__(256)
__global__ void k_localcsr(const int2* __restrict__ binned, const int* __restrict__ bbase,
                           int* __restrict__ rp, int* __restrict__ csr,
                           float* __restrict__ dinv, int n, int e){
  __shared__ int cnt[RB];
  __shared__ int sh[256];
  __shared__ int cur[RB];
  int b = blockIdx.x, t = threadIdx.x;
  int node0 = b<<RB_SHIFT;
  int e0 = bbase[b], e1 = bbase[b+1];
  cnt[t]=0; cnt[t+256]=0;
  __syncthreads();
  for(int i=e0+t; i<e1; i+=256)
    atomicAdd(&cnt[binned[i].x - node0], 1);
  __syncthreads();
  int c0 = cnt[2*t], c1 = cnt[2*t+1];
  int s = c0+c1;
  sh[t]=s;
  __syncthreads();
  for(int off=1; off<256; off<<=1){
    int v = (t>=off)? sh[t-off]:0;
    __syncthreads();
    sh[t]+=v;
    __syncthreads();
  }
  int excl = sh[t]-s;
  int g0 = node0+2*t, g1 = node0+2*t+1;
  if(g0<n){ rp[g0]=e0+excl;    dinv[g0]=rsqrtf((float)(c0+1)); }
  if(g1<n){ rp[g1]=e0+excl+c0; dinv[g1]=rsqrtf((float)(c1+1)); }
  cur[2*t]=excl; cur[2*t+1]=excl+c0;
  if(b==0 && t==0) rp[n]=e;
  __syncthreads();
  for(int i=e0+t; i<e1; i+=256){
    int2 pr = binned[i];
    int lp = atomicAdd(&cur[pr.x - node0], 1);
    csr[e0+lp] = pr.y;
  }
}

// ---------------- prescale: g0 = dinv .* x ----------------

__global__ void k_prescale(const float* __restrict__ x, const float* __restrict__ dinv,
                           float* __restrict__ g, int n){
  int i = blockIdx.x*256 + threadIdx.x;     // float4 index
  if(i < n*(DF/4)){
    float4 v = ((const float4*)x)[i];
    float dv = dinv[i>>5];
    v.x*=dv; v.y*=dv; v.z*=dv; v.w*=dv;
    ((float4*)g)[i] = v;
  }
}

// ---------------- Fused layer, software-pipelined ----------------
// Each wave (64 lanes, float2/lane = one 128-f32 row) owns 16 nodes = 4 quads.
// While gathering quad q (4 independent edge chains, 1 load/node/batch), the
// wave executes GEMM chunks of quad q-1 in the load shadows. zs double-buffered
// per group; wave-local sync only. Breaks the gather/GEMM convoy.

__launch_bounds__(256, 4)
__global__ void k_fused(const float* __restrict__ g, const int* __restrict__ rp,
                        const int* __restrict__ cs, const float* __restrict__ dinv,
                        const float* __restrict__ W, const float* __restrict__ bias,
                        float* __restrict__ out, int n, int scale_out){
  __shared__ float zs[4][8][132];
  int t = threadIdx.x;
  int grp = t>>6, lane = t&63;
  const float2* gv = (const float2*)g;
  const float2* Wv = (const float2*)W;
  float2* out2 = (float2*)out;
  float2 bz = ((const float2*)bias)[lane];
  int nodeBase = blockIdx.x*64 + grp*16;

  float2 y0,y1,y2,y3;
  y0=y1=y2=y3=make_float2(0.f,0.f);
  int pn0=n,pn1=n,pn2=n,pn3=n;       // prev quad node ids (guarded off initially)
  int prb = 0;                       // prev quad LDS row base (0/4)

  // one GEMM chunk = 2 k-quads (8 k values) of the prev quad
#define GCHUNK(KB) {                                                        \
    const float4 z0 = *(const float4*)&zs[grp][prb+0][KB];                  \
    const float4 z1 = *(const float4*)&zs[grp][prb+1][KB];                  \
    const float4 z2 = *(const float4*)&zs[grp][prb+2][KB];                  \
    const float4 z3 = *(const float4*)&zs[grp][prb+3][KB];                  \
    float2 w0 = Wv[(KB+0)*64+lane];  float2 w1 = Wv[(KB+1)*64+lane];        \
    float2 w2 = Wv[(KB+2)*64+lane];  float2 w3 = Wv[(KB+3)*64+lane];        \
    y0.x=fmaf(z0.x,w0.x,y0.x); y0.y=fmaf(z0.x,w0.y,y0.y);                   \
    y0.x=fmaf(z0.y,w1.x,y0.x); y0.y=fmaf(z0.y,w1.y,y0.y);                   \
    y0.x=fmaf(z0.z,w2.x,y0.x); y0.y=fmaf(z0.z,w2.y,y0.y);                   \
    y0.x=fmaf(z0.w,w3.x,y0.x); y0.y=fmaf(z0.w,w3.y,y0.y);                   \
    y1.x=fmaf(z1.x,w0.x,y1.x); y1.y=fmaf(z1.x,w0.y,y1.y);                   \
    y1.x=fmaf(z1.y,w1.x,y1.x); y1.y=fmaf(z1.y,w1.y,y1.y);                   \
    y1.x=fmaf(z1.z,w2.x,y1.x); y1.y=fmaf(z1.z,w2.y,y1.y);                   \
    y1.x=fmaf(z1.w,w3.x,y1.x); y1.y=fmaf(z1.w,w3.y,y1.y);                   \
    y2.x=fmaf(z2.x,w0.x,y2.x); y2.y=fmaf(z2.x,w0.y,y2.y);                   \
    y2.x=fmaf(z2.y,w1.x,y2.x); y2.y=fmaf(z2.y,w1.y,y2.y);                   \
    y2.x=fmaf(z2.z,w2.x,y2.x); y2.y=fmaf(z2.z,w2.y,y2.y);                   \
    y2.x=fmaf(z2.w,w3.x,y2.x); y2.y=fmaf(z2.w,w3.y,y2.y);                   \
    y3.x=fmaf(z3.x,w0.x,y3.x); y3.y=fmaf(z3.x,w0.y,y3.y);                   \
    y3.x=fmaf(z3.y,w1.x,y3.x); y3.y=fmaf(z3.y,w1.y,y3.y);                   \
    y3.x=fmaf(z3.z,w2.x,y3.x); y3.y=fmaf(z3.z,w2.y,y3.y);                   \
    y3.x=fmaf(z3.w,w3.x,y3.x); y3.y=fmaf(z3.w,w3.y,y3.y); }

  for(int q=0; q<5; ++q){
    const bool doG = (q<4);
    const bool doM = (q>0);
    int kq = 0;
    // ---- gather setup ----
    int n0=0,n1=0,n2=0,n3=0, p0=0,p1=0,p2=0,p3=0, e0=0,e1=0,e2=0,e3=0;
    float2 A0,A1,A2,A3;
    A0=A1=A2=A3=make_float2(0.f,0.f);
    if(doG){
      n0=nodeBase+q*4; n1=n0+1; n2=n0+2; n3=n0+3;
      p0=(n0<n)?rp[n0]:0; e0=(n0<n)?rp[n0+1]:0;
      p1=(n1<n)?rp[n1]:0; e1=(n1<n)?rp[n1+1]:0;
      p2=(n2<n)?rp[n2]:0; e2=(n2<n)?rp[n2+1]:0;
      p3=(n3<n)?rp[n3]:0; e3=(n3<n)?rp[n3+1]:0;
      // batch -1: self rows
      float2 v0,v1,v2,v3;
      v0=v1=v2=v3=make_float2(0.f,0.f);
      if(n0<n) v0 = gv[(size_t)n0*64+lane];
      if(n1<n) v1 = gv[(size_t)n1*64+lane];
      if(n2<n) v2 = gv[(size_t)n2*64+lane];
      if(n3<n) v3 = gv[(size_t)n3*64+lane];
      if(doM && kq<128){ GCHUNK(kq); GCHUNK(kq+4); kq+=8; }
      A0.x+=v0.x; A0.y+=v0.y; A1.x+=v1.x; A1.y+=v1.y;
      A2.x+=v2.x; A2.y+=v2.y; A3.x+=v3.x; A3.y+=v3.y;
      // edge batches, round-robin over the 4 chains
      while(p0<e0 || p1<e1 || p2<e2 || p3<e3){
        bool b0=p0<e0, b1=p1<e1, b2=p2<e2, b3=p3<e3;
        if(b0) v0 = gv[(size_t)cs[p0]*64+lane];
        if(b1) v1 = gv[(size_t)cs[p1]*64+lane];
        if(b2) v2 = gv[(size_t)cs[p2]*64+lane];
        if(b3) v3 = gv[(size_t)cs[p3]*64+lane];
        if(doM && kq<128){ GCHUNK(kq); GCHUNK(kq+4); kq+=8; }
        if(b0){ A0.x+=v0.x; A0.y+=v0.y; p0++; }
        if(b1){ A1.x+=v1.x; A1.y+=v1.y; p1++; }
        if(b2){ A2.x+=v2.x; A2.y+=v2.y; p2++; }
        if(b3){ A3.x+=v3.x; A3.y+=v3.y; p3++; }
      }
    }
    // ---- GEMM drain for prev quad ----
    if(doM){
      while(kq<128){ GCHUNK(kq); GCHUNK(kq+4); kq+=8; }
      // epilogue: bias + relu (+ dinv scale), store
      if(pn0<n){ float2 o; o.x=fmaxf(y0.x+bz.x,0.f); o.y=fmaxf(y0.y+bz.y,0.f);
                 if(scale_out){ float d=dinv[pn0]; o.x*=d; o.y*=d; }
                 out2[(size_t)pn0*64+lane]=o; }
      if(pn1<n){ float2 o; o.x=fmaxf(y1.x+bz.x,0.f); o.y=fmaxf(y1.y+bz.y,0.f);
                 if(scale_out){ float d=dinv[pn1]; o.x*=d; o.y*=d; }
                 out2[(size_t)pn1*64+lane]=o; }
      if(pn2<n){ float2 o; o.x=fmaxf(y2.x+bz.x,0.f); o.y=fmaxf(y2.y+bz.y,0.f);
                 if(scale_out){ float d=dinv[pn2]; o.x*=d; o.y*=d; }
                 out2[(size_t)pn2*64+lane]=o; }
      if(pn3<n){ float2 o; o.x=fmaxf(y3.x+bz.x,0.f); o.y=fmaxf(y3.y+bz.y,0.f);
                 if(scale_out){ float d=dinv[pn3]; o.x*=d; o.y*=d; }
                 out2[(size_t)pn3*64+lane]=o; }
      y0=y1=y2=y3=make_float2(0.f,0.f);
    }
    // ---- finish gather quad: scale + zs write + wave-local sync ----
    if(doG){
      int rb=(q&1)*4;
      float d0=(n0<n)?dinv[n0]:0.f, d1=(n1<n)?dinv[n1]:0.f;
      float d2=(n2<n)?dinv[n2]:0.f, d3=(n3<n)?dinv[n3]:0.f;
      *(float2*)&zs[grp][rb+0][2*lane] = make_float2(A0.x*d0, A0.y*d0);
      *(float2*)&zs[grp][rb+1][2*lane] = make_float2(A1.x*d1, A1.y*d1);
      *(float2*)&zs[grp][rb+2][2*lane] = make_float2(A2.x*d2, A2.y*d2);
      *(float2*)&zs[grp][rb+3][2*lane] = make_float2(A3.x*d3, A3.y*d3);
      asm volatile("s_waitcnt lgkmcnt(0)" ::: "memory");
      __builtin_amdgcn_wave_barrier();
      __builtin_amdgcn_sched_barrier(0);
      pn0=n0; pn1=n1; pn2=n2; pn3=n3; prb=rb;
    }
  }
#undef GCHUNK
}

// ---------------- Final layer: 128 -> 5 ----------------

__launch_bounds__(256)
__global__ void k_gemm5(const float* __restrict__ X, const float* __restrict__ W2,
                        const float* __restrict__ dinv, float* __restrict__ out, int n){
  __shared__ float xs[32][129];
  __shared__ float wsh[640];
  int t=threadIdx.x;
  int row0=blockIdx.x*32;
  for(int idx=t; idx<640; idx+=256) wsh[idx]=W2[idx];
  for(int idx=t; idx<1024; idx+=256){
    int r=idx>>5, k4=(idx&31)*4;
    int gr=row0+r;
    float4 v = (gr<n)? *(const float4*)(X+(size_t)gr*DF+k4) : make_float4(0.f,0.f,0.f,0.f);
    xs[r][k4]=v.x; xs[r][k4+1]=v.y; xs[r][k4+2]=v.z; xs[r][k4+3]=v.w;
  }
  __syncthreads();
  int r=t>>3, c=t&7;
  int gr=row0+r;
  if(c<5 && gr<n){
    float acc=0.f;
    #pragma unroll
    for(int k=0;k<128;k++) acc = fmaf(xs[r][k], wsh[k*5+c], acc);
    out[(size_t)gr*5+c] = dinv[gr]*acc;
  }
}

__global__ void k_agg5(const float* __restrict__ ht, const int* __restrict__ rp,
                       const int* __restrict__ cs, const float* __restrict__ dinv,
                       const float* __restrict__ b2, float* __restrict__ out, int n){
  int idx = blockIdx.x*256+threadIdx.x;
  int node = idx>>3, c = idx&7;
  if(node>=n || c>=5) return;
  float acc = ht[(size_t)node*5+c];
  int e0=rp[node], e1=rp[node+1];
  for(int e=e0;e<e1;e++){
    acc += ht[(size_t)cs[e]*5+c];
  }
  out[(size_t)node*5+c] = fmaf(dinv[node], acc, b2[c]);
}

// ---------------- launch ----------------

extern "C" void kernel_launch(void* const* d_in, const int* in_sizes, int n_in,
                              void* d_out, int out_size, void* d_ws, size_t ws_size,
                              hipStream_t stream){
  const float* x  = (const float*)d_in[0];
  const int*   ei = (const int*)  d_in[1];
  const float* W0 = (const float*)d_in[2];
  const float* b0 = (const float*)d_in[3];
  const float* W1 = (const float*)d_in[4];
  const float* b1 = (const float*)d_in[5];
  const float* W2 = (const float*)d_in[6];
  const float* b2 = (const float*)d_in[7];
  int n = in_sizes[0]/DF;
  int e = in_sizes[1]/2;
  const int* srcp = ei;
  const int* dstp = ei + e;

  char* ws = (char*)d_ws;
  size_t off=0;
  auto take=[&](size_t bytes)->char*{
    char* p = ws+off;
    off = (off+bytes+511)&~(size_t)511;
    return p;
  };
  int*   bcnt = (int*)  take((size_t)NB_MAX*4);
  int*   bbase= (int*)  take((size_t)(NB_MAX+1)*4);
  int*   bcur = (int*)  take((size_t)NB_MAX*4);
  int*   rp   = (int*)  take((size_t)(n+1)*4);
  int*   csr  = (int*)  take((size_t)e*4);
  float* dinv = (float*)take((size_t)n*4);
  float* bufA = (float*)take((size_t)n*DF*4);
  float* bufB = (float*)take((size_t)n*DF*4);
  int2*  binned = (int2*)bufB;   // dead before first write of bufB

  hipMemsetAsync(bcnt, 0, (size_t)NB_MAX*4, stream);

  int nb   = (n + RB-1) >> RB_SHIFT;
  int ncb  = (e + CHUNK-1) / CHUNK;
  k_bhist     <<<ncb, 256, 0, stream>>>(dstp, bcnt, e);
  k_bscan     <<<1,   256, 0, stream>>>(bcnt, bbase, bcur, e);
  k_binscatter<<<ncb, 256, 0, stream>>>(srcp, dstp, bcur, binned, e);
  k_localcsr  <<<nb,  256, 0, stream>>>(binned, bbase, rp, csr, dinv, n, e);

  int nfb = (n+63)/64;
  k_prescale<<<(n*(DF/4)+255)/256, 256, 0, stream>>>(x, dinv, bufA, n);
  // layer 1: gather g0(bufA) -> bufB = dinv*relu(y)
  k_fused   <<<nfb, 256, 0, stream>>>(bufA, rp, csr, dinv, W0, b0, bufB, n, 1);
  // layer 2: gather g1(bufB) -> bufA = relu(y)  (plain h2)
  k_fused   <<<nfb, 256, 0, stream>>>(bufB, rp, csr, dinv, W1, b1, bufA, n, 0);
  // layer 3: ht = dinv*(h2 @ W2) in bufB, then aggregate
  k_gemm5   <<<(n+31)/32, 256, 0, stream>>>(bufA, W2, dinv, (float*)bufB, n);
  k_agg5    <<<((n*8)+255)/256, 256, 0, stream>>>((float*)bufB, rp, csr, dinv, b2, (float*)d_out, n);
}

// Round 11
// 456.640 us; speedup vs baseline: 1.6115x; 1.6115x over previous
//
#include <hip/hip_runtime.h>

#define DF 128
#define RB 512            // nodes per bucket (power of two)
#define RB_SHIFT 9
#define NB_MAX 256        // supports n <= 131072
#define CHUNK 8192        // edges per binning block

// ---------------- CSR build (bucketed, coalesced) ----------------

__global__ void k_bhist(const int* __restrict__ dst, int* __restrict__ bcnt, int e){
  __shared__ int h[NB_MAX];
  int t = threadIdx.x;
  h[t] = 0;
  __syncthreads();
  int base = blockIdx.x*CHUNK;
  for(int k=0;k<CHUNK/256;k++){
    int i = base + t + k*256;
    if(i<e) atomicAdd(&h[dst[i]>>RB_SHIFT], 1);
  }
  __syncthreads();
  if(h[t]) atomicAdd(&bcnt[t], h[t]);
}

__global__ void k_bscan(const int* __restrict__ bcnt, int* __restrict__ bbase,
                        int* __restrict__ bcur, int e){
  __shared__ int sh[NB_MAX];
  int t = threadIdx.x;
  int c = bcnt[t];
  sh[t] = c;
  __syncthreads();
  for(int off=1; off<256; off<<=1){
    int v = (t>=off)? sh[t-off]:0;
    __syncthreads();
    sh[t]+=v;
    __syncthreads();
  }
  int excl = sh[t]-c;
  bbase[t]=excl; bcur[t]=excl;
  if(t==255) bbase[256]=sh[255];   // == e
}

__launch_bounds__(256)
__global__ void k_binscatter(const int* __restrict__ src, const int* __restrict__ dst,
                             int* __restrict__ bcur, int2* __restrict__ binned, int e){
  __shared__ int h[NB_MAX];
  __shared__ int lexcl[NB_MAX];
  __shared__ int lcur[NB_MAX];
  __shared__ int gbase[NB_MAX];
  __shared__ int2 pairs[CHUNK];
  int t = threadIdx.x;
  int c0 = blockIdx.x*CHUNK;
  int cc = min(CHUNK, e - c0);
  h[t]=0;
  __syncthreads();
  for(int k=0;k<CHUNK/256;k++){
    int i = t + k*256;
    if(i<cc) atomicAdd(&h[dst[c0+i]>>RB_SHIFT], 1);
  }
  __syncthreads();
  int hc = h[t];
  lexcl[t]=hc;
  __syncthreads();
  for(int off=1; off<256; off<<=1){
    int v = (t>=off)? lexcl[t-off]:0;
    __syncthreads();
    lexcl[t]+=v;
    __syncthreads();
  }
  int incl = lexcl[t];
  lexcl[t] = incl - hc;
  lcur[t]  = incl - hc;
  gbase[t] = hc ? atomicAdd(&bcur[t], hc) : 0;
  __syncthreads();
  for(int k=0;k<CHUNK/256;k++){
    int i = t + k*256;
    if(i<cc){
      int d = dst[c0+i], s = src[c0+i];
      int lp = atomicAdd(&lcur[d>>RB_SHIFT], 1);
      pairs[lp] = make_int2(d, s);
    }
  }
  __syncthreads();
  for(int k=0;k<CHUNK/256;k++){
    int p = t + k*256;
    if(p<cc){
      int2 pr = pairs[p];
      int b = pr.x>>RB_SHIFT;
      binned[gbase[b] + (p - lexcl[b])] = pr;
    }
  }
}

__launch_bounds__(256)
__global__ void k_localcsr(const int2* __restrict__ binned, const int* __restrict__ bbase,
                           int* __restrict__ rp, int* __restrict__ csr,
                           float* __restrict__ dinv, int n, int e){
  __shared__ int cnt[RB];
  __shared__ int sh[256];
  __shared__ int cur[RB];
  int b = blockIdx.x, t = threadIdx.x;
  int node0 = b<<RB_SHIFT;
  int e0 = bbase[b], e1 = bbase[b+1];
  cnt[t]=0; cnt[t+256]=0;
  __syncthreads();
  for(int i=e0+t; i<e1; i+=256)
    atomicAdd(&cnt[binned[i].x - node0], 1);
  __syncthreads();
  int c0 = cnt[2*t], c1 = cnt[2*t+1];
  int s = c0+c1;
  sh[t]=s;
  __syncthreads();
  for(int off=1; off<256; off<<=1){
    int v = (t>=off)? sh[t-off]:0;
    __syncthreads();
    sh[t]+=v;
    __syncthreads();
  }
  int excl = sh[t]-s;
  int g0 = node0+2*t, g1 = node0+2*t+1;
  if(g0<n){ rp[g0]=e0+excl;    dinv[g0]=rsqrtf((float)(c0+1)); }
  if(g1<n){ rp[g1]=e0+excl+c0; dinv[g1]=rsqrtf((float)(c1+1)); }
  cur[2*t]=excl; cur[2*t+1]=excl+c0;
  if(b==0 && t==0) rp[n]=e;
  __syncthreads();
  for(int i=e0+t; i<e1; i+=256){
    int2 pr = binned[i];
    int lp = atomicAdd(&cur[pr.x - node0], 1);
    csr[e0+lp] = pr.y;
  }
}

// ---------------- prescale: g0 = dinv .* x ----------------

__global__ void k_prescale(const float* __restrict__ x, const float* __restrict__ dinv,
                           float* __restrict__ g, int n){
  int i = blockIdx.x*256 + threadIdx.x;     // float4 index
  if(i < n*(DF/4)){
    float4 v = ((const float4*)x)[i];
    float dv = dinv[i>>5];
    v.x*=dv; v.y*=dv; v.z*=dv; v.w*=dv;
    ((float4*)g)[i] = v;
  }
}

// ---------------- Fused layer: gather(g) -> z=dv*s -> y=zW+b -> act ----------------
// R6/R8 structure; gather uses an explicit 4-deep rotating prefetch so each
// wave keeps 4-8 row-loads in flight (R9's version was VGPR-capped to 32 by
// launch_bounds(,8) and re-serialized). bounds(,6): VGPR cap ~85, occ ~75%.

#define ROWLD(J) (*(const float4*)(g + (size_t)cs[e0+(J)]*DF + c4))

__launch_bounds__(256, 6)
__global__ void k_fused(const float* __restrict__ g, const int* __restrict__ rp,
                        const int* __restrict__ cs, const float* __restrict__ dinv,
                        const float* __restrict__ W, const float* __restrict__ bias,
                        float* __restrict__ out, int n, int scale_out){
  __shared__ float zs[32][132];
  int t = threadIdx.x;
  int grp = t>>5, lane = t&31;
  int node0 = blockIdx.x*32;
  int c4 = lane*4;
  // ---- phase 1: gather (group-private rows zs[grp*4 .. grp*4+3]) ----
  for(int nn=0; nn<4; nn++){
    int node = node0 + grp*4 + nn;
    if(node<n){
      float4 A0 = *(const float4*)(g + (size_t)node*DF + c4);   // self (pre-scaled)
      float4 A1 = make_float4(0.f,0.f,0.f,0.f);
      float4 A2 = A1, A3 = A1;
      int e0=rp[node];
      int L = rp[node+1]-e0;
      float4 p0=A1, p1=A1, p2=A1, p3=A1;
      if(L>0) p0=ROWLD(0);
      if(L>1) p1=ROWLD(1);
      if(L>2) p2=ROWLD(2);
      if(L>3) p3=ROWLD(3);
      int i=0;
      for(; i+8<=L; i+=4){
        float4 q0=ROWLD(i+4), q1=ROWLD(i+5), q2=ROWLD(i+6), q3=ROWLD(i+7);
        A0.x+=p0.x; A0.y+=p0.y; A0.z+=p0.z; A0.w+=p0.w;
        A1.x+=p1.x; A1.y+=p1.y; A1.z+=p1.z; A1.w+=p1.w;
        A2.x+=p2.x; A2.y+=p2.y; A2.z+=p2.z; A2.w+=p2.w;
        A3.x+=p3.x; A3.y+=p3.y; A3.z+=p3.z; A3.w+=p3.w;
        p0=q0; p1=q1; p2=q2; p3=q3;
      }
      // after loop: p0..p3 cover positions i..i+3 (zero where >= L)
      if(i+0<L){ A0.x+=p0.x; A0.y+=p0.y; A0.z+=p0.z; A0.w+=p0.w; }
      if(i+1<L){ A1.x+=p1.x; A1.y+=p1.y; A1.z+=p1.z; A1.w+=p1.w; }
      if(i+2<L){ A2.x+=p2.x; A2.y+=p2.y; A2.z+=p2.z; A2.w+=p2.w; }
      if(i+3<L){ A3.x+=p3.x; A3.y+=p3.y; A3.z+=p3.z; A3.w+=p3.w; }
      for(int j=i+4; j<L; j++){
        float4 v=ROWLD(j);
        A0.x+=v.x; A0.y+=v.y; A0.z+=v.z; A0.w+=v.w;
      }
      float dv = dinv[node];
      float4 zv;
      zv.x = dv*((A0.x+A1.x)+(A2.x+A3.x));
      zv.y = dv*((A0.y+A1.y)+(A2.y+A3.y));
      zv.z = dv*((A0.z+A1.z)+(A2.z+A3.z));
      zv.w = dv*((A0.w+A1.w)+(A2.w+A3.w));
      *(float4*)&zs[grp*4+nn][c4] = zv;
    }
  }
  // wave-local LDS sync: rows are written and read by the same wave.
  asm volatile("s_waitcnt lgkmcnt(0)" ::: "memory");
  __builtin_amdgcn_wave_barrier();
  __builtin_amdgcn_sched_barrier(0);
  // ---- phase 2: y = z @ W + b ----
  const float4* Wr = (const float4*)W;      // [128][32] float4 view
  int r0 = grp*4;
  float4 a0 = make_float4(0.f,0.f,0.f,0.f);
  float4 a1 = a0, a2 = a0, a3 = a0;
  for(int k=0;k<128;k+=4){
    float4 s0 = *(const float4*)&zs[r0  ][k];
    float4 s1 = *(const float4*)&zs[r0+1][k];
    float4 s2 = *(const float4*)&zs[r0+2][k];
    float4 s3 = *(const float4*)&zs[r0+3][k];
#define STEP(KK, C) { float4 w = Wr[(k+KK)*32 + lane];                     \
    a0.x = fmaf(s0.C, w.x, a0.x); a0.y = fmaf(s0.C, w.y, a0.y);            \
    a0.z = fmaf(s0.C, w.z, a0.z); a0.w = fmaf(s0.C, w.w, a0.w);            \
    a1.x = fmaf(s1.C, w.x, a1.x); a1.y = fmaf(s1.C, w.y, a1.y);            \
    a1.z = fmaf(s1.C, w.z, a1.z); a1.w = fmaf(s1.C, w.w, a1.w);            \
    a2.x = fmaf(s2.C, w.x, a2.x); a2.y = fmaf(s2.C, w.y, a2.y);            \
    a2.z = fmaf(s2.C, w.z, a2.z); a2.w = fmaf(s2.C, w.w, a2.w);            \
    a3.x = fmaf(s3.C, w.x, a3.x); a3.y = fmaf(s3.C, w.y, a3.y);            \
    a3.z = fmaf(s3.C, w.z, a3.z); a3.w = fmaf(s3.C, w.w, a3.w); }
    STEP(0, x) STEP(1, y) STEP(2, z) STEP(3, w)
#undef STEP
  }
  float4 bz = ((const float4*)bias)[lane];
  float4 av[4] = {a0, a1, a2, a3};
  for(int nn=0; nn<4; nn++){
    int node = node0 + r0 + nn;
    if(node<n){
      float4 y = av[nn];
      y.x += bz.x; y.y += bz.y; y.z += bz.z; y.w += bz.w;
      y.x = fmaxf(y.x, 0.f); y.y = fmaxf(y.y, 0.f);
      y.z = fmaxf(y.z, 0.f); y.w = fmaxf(y.w, 0.f);
      if(scale_out){
        float dv = dinv[node];
        y.x*=dv; y.y*=dv; y.z*=dv; y.w*=dv;
      }
      *(float4*)(out + (size_t)node*DF + c4) = y;
    }
  }
}
#undef ROWLD

// ---------------- Final layer: 128 -> 5 ----------------

__launch_bounds__(256)
__global__ void k_gemm5(const float* __restrict__ X, const float* __restrict__ W2,
                        const float* __restrict__ dinv, float* __restrict__ out, int n){
  __shared__ float xs[32][129];
  __shared__ float wsh[640];
  int t=threadIdx.x;
  int row0=blockIdx.x*32;
  for(int idx=t; idx<640; idx+=256) wsh[idx]=W2[idx];
  for(int idx=t; idx<1024; idx+=256){
    int r=idx>>5, k4=(idx&31)*4;
    int gr=row0+r;
    float4 v = (gr<n)? *(const float4*)(X+(size_t)gr*DF+k4) : make_float4(0.f,0.f,0.f,0.f);
    xs[r][k4]=v.x; xs[r][k4+1]=v.y; xs[r][k4+2]=v.z; xs[r][k4+3]=v.w;
  }
  __syncthreads();
  int r=t>>3, c=t&7;
  int gr=row0+r;
  if(c<5 && gr<n){
    float acc=0.f;
    #pragma unroll
    for(int k=0;k<128;k++) acc = fmaf(xs[r][k], wsh[k*5+c], acc);
    out[(size_t)gr*5+c] = dinv[gr]*acc;
  }
}

__global__ void k_agg5(const float* __restrict__ ht, const int* __restrict__ rp,
                       const int* __restrict__ cs, const float* __restrict__ dinv,
                       const float* __restrict__ b2, float* __restrict__ out, int n){
  int idx = blockIdx.x*256+threadIdx.x;
  int node = idx>>3, c = idx&7;
  if(node>=n || c>=5) return;
  float acc = ht[(size_t)node*5+c];
  int e0=rp[node], e1=rp[node+1];
  for(int e=e0;e<e1;e++){
    acc += ht[(size_t)cs[e]*5+c];
  }
  out[(size_t)node*5+c] = fmaf(dinv[node], acc, b2[c]);
}

// ---------------- launch ----------------

extern "C" void kernel_launch(void* const* d_in, const int* in_sizes, int n_in,
                              void* d_out, int out_size, void* d_ws, size_t ws_size,
                              hipStream_t stream){
  const float* x  = (const float*)d_in[0];
  const int*   ei = (const int*)  d_in[1];
  const float* W0 = (const float*)d_in[2];
  const float* b0 = (const float*)d_in[3];
  const float* W1 = (const float*)d_in[4];
  const float* b1 = (const float*)d_in[5];
  const float* W2 = (const float*)d_in[6];
  const float* b2 = (const float*)d_in[7];
  int n = in_sizes[0]/DF;
  int e = in_sizes[1]/2;
  const int* srcp = ei;
  const int* dstp = ei + e;

  char* ws = (char*)d_ws;
  size_t off=0;
  auto take=[&](size_t bytes)->char*{
    char* p = ws+off;
    off = (off+bytes+511)&~(size_t)511;
    return p;
  };
  int*   bcnt = (int*)  take((size_t)NB_MAX*4);
  int*   bbase= (int*)  take((size_t)(NB_MAX+1)*4);
  int*   bcur = (int*)  take((size_t)NB_MAX*4);
  int*   rp   = (int*)  take((size_t)(n+1)*4);
  int*   csr  = (int*)  take((size_t)e*4);
  float* dinv = (float*)take((size_t)n*4);
  float* bufA = (float*)take((size_t)n*DF*4);
  float* bufB = (float*)take((size_t)n*DF*4);
  int2*  binned = (int2*)bufB;   // dead before first write of bufB

  hipMemsetAsync(bcnt, 0, (size_t)NB_MAX*4, stream);

  int nb   = (n + RB-1) >> RB_SHIFT;
  int ncb  = (e + CHUNK-1) / CHUNK;
  k_bhist     <<<ncb, 256, 0, stream>>>(dstp, bcnt, e);
  k_bscan     <<<1,   256, 0, stream>>>(bcnt, bbase, bcur, e);
  k_binscatter<<<ncb, 256, 0, stream>>>(srcp, dstp, bcur, binned, e);
  k_localcsr  <<<nb,  256, 0, stream>>>(binned, bbase, rp, csr, dinv, n, e);

  int nfb = (n+31)/32;
  k_prescale<<<(n*(DF/4)+255)/256, 256, 0, stream>>>(x, dinv, bufA, n);
  // layer 1: gather g0(bufA) -> bufB = dinv*relu(y)
  k_fused   <<<nfb, 256, 0, stream>>>(bufA, rp, csr, dinv, W0, b0, bufB, n, 1);
  // layer 2: gather g1(bufB) -> bufA = relu(y)  (plain h2)
  k_fused   <<<nfb, 256, 0, stream>>>(bufB, rp, csr, dinv, W1, b1, bufA, n, 0);
  // layer 3: ht = dinv*(h2 @ W2) in bufB, then aggregate
  k_gemm5   <<<(n+31)/32, 256, 0, stream>>>(bufA, W2, dinv, (float*)bufB, n);
  k_agg5    <<<((n*8)+255)/256, 256, 0, stream>>>((float*)bufB, rp, csr, dinv, b2, (float*)d_out, n);
}

// Round 12
// 423.854 us; speedup vs baseline: 1.7361x; 1.0774x over previous
//
#include <hip/hip_runtime.h>
#include <hip/hip_fp16.h>

#define DF 128
#define RB 512            // nodes per bucket (power of two)
#define RB_SHIFT 9
#define NB_MAX 256        // supports n <= 131072
#define CHUNK 8192        // edges per binning block

struct h2x2 { __half2 a, b; };   // 8 bytes = 4 halves

// ---------------- CSR build (bucketed, coalesced) ----------------

__global__ void k_bhist(const int* __restrict__ dst, int* __restrict__ bcnt, int e){
  __shared__ int h[NB_MAX];
  int t = threadIdx.x;
  h[t] = 0;
  __syncthreads();
  int base = blockIdx.x*CHUNK;
  for(int k=0;k<CHUNK/256;k++){
    int i = base + t + k*256;
    if(i<e) atomicAdd(&h[dst[i]>>RB_SHIFT], 1);
  }
  __syncthreads();
  if(h[t]) atomicAdd(&bcnt[t], h[t]);
}

__global__ void k_bscan(const int* __restrict__ bcnt, int* __restrict__ bbase,
                        int* __restrict__ bcur, int e){
  __shared__ int sh[NB_MAX];
  int t = threadIdx.x;
  int c = bcnt[t];
  sh[t] = c;
  __syncthreads();
  for(int off=1; off<256; off<<=1){
    int v = (t>=off)? sh[t-off]:0;
    __syncthreads();
    sh[t]+=v;
    __syncthreads();
  }
  int excl = sh[t]-c;
  bbase[t]=excl; bcur[t]=excl;
  if(t==255) bbase[256]=sh[255];   // == e
}

__launch_bounds__(256)
__global__ void k_binscatter(const int* __restrict__ src, const int* __restrict__ dst,
                             int* __restrict__ bcur, int2* __restrict__ binned, int e){
  __shared__ int h[NB_MAX];
  __shared__ int lexcl[NB_MAX];
  __shared__ int lcur[NB_MAX];
  __shared__ int gbase[NB_MAX];
  __shared__ int2 pairs[CHUNK];
  int t = threadIdx.x;
  int c0 = blockIdx.x*CHUNK;
  int cc = min(CHUNK, e - c0);
  h[t]=0;
  __syncthreads();
  for(int k=0;k<CHUNK/256;k++){
    int i = t + k*256;
    if(i<cc) atomicAdd(&h[dst[c0+i]>>RB_SHIFT], 1);
  }
  __syncthreads();
  int hc = h[t];
  lexcl[t]=hc;
  __syncthreads();
  for(int off=1; off<256; off<<=1){
    int v = (t>=off)? lexcl[t-off]:0;
    __syncthreads();
    lexcl[t]+=v;
    __syncthreads();
  }
  int incl = lexcl[t];
  lexcl[t] = incl - hc;
  lcur[t]  = incl - hc;
  gbase[t] = hc ? atomicAdd(&bcur[t], hc) : 0;
  __syncthreads();
  for(int k=0;k<CHUNK/256;k++){
    int i = t + k*256;
    if(i<cc){
      int d = dst[c0+i], s = src[c0+i];
      int lp = atomicAdd(&lcur[d>>RB_SHIFT], 1);
      pairs[lp] = make_int2(d, s);
    }
  }
  __syncthreads();
  for(int k=0;k<CHUNK/256;k++){
    int p = t + k*256;
    if(p<cc){
      int2 pr = pairs[p];
      int b = pr.x>>RB_SHIFT;
      binned[gbase[b] + (p - lexcl[b])] = pr;
    }
  }
}

__launch_bounds__(256)
__global__ void k_localcsr(const int2* __restrict__ binned, const int* __restrict__ bbase,
                           int* __restrict__ rp, int* __restrict__ csr,
                           float* __restrict__ dinv, int n, int e){
  __shared__ int cnt[RB];
  __shared__ int sh[256];
  __shared__ int cur[RB];
  int b = blockIdx.x, t = threadIdx.x;
  int node0 = b<<RB_SHIFT;
  int e0 = bbase[b], e1 = bbase[b+1];
  cnt[t]=0; cnt[t+256]=0;
  __syncthreads();
  for(int i=e0+t; i<e1; i+=256)
    atomicAdd(&cnt[binned[i].x - node0], 1);
  __syncthreads();
  int c0 = cnt[2*t], c1 = cnt[2*t+1];
  int s = c0+c1;
  sh[t]=s;
  __syncthreads();
  for(int off=1; off<256; off<<=1){
    int v = (t>=off)? sh[t-off]:0;
    __syncthreads();
    sh[t]+=v;
    __syncthreads();
  }
  int excl = sh[t]-s;
  int g0 = node0+2*t, g1 = node0+2*t+1;
  if(g0<n){ rp[g0]=e0+excl;    dinv[g0]=rsqrtf((float)(c0+1)); }
  if(g1<n){ rp[g1]=e0+excl+c0; dinv[g1]=rsqrtf((float)(c1+1)); }
  cur[2*t]=excl; cur[2*t+1]=excl+c0;
  if(b==0 && t==0) rp[n]=e;
  __syncthreads();
  for(int i=e0+t; i<e1; i+=256){
    int2 pr = binned[i];
    int lp = atomicAdd(&cur[pr.x - node0], 1);
    csr[e0+lp] = pr.y;
  }
}

// ---------------- prescale: g0 = dinv .* x ----------------

__global__ void k_prescale(const float* __restrict__ x, const float* __restrict__ dinv,
                           float* __restrict__ g, int n){
  int i = blockIdx.x*256 + threadIdx.x;     // float4 index
  if(i < n*(DF/4)){
    float4 v = ((const float4*)x)[i];
    float dv = dinv[i>>5];
    v.x*=dv; v.y*=dv; v.z*=dv; v.w*=dv;
    ((float4*)g)[i] = v;
  }
}

// ---------------- Fused layer (R8 structure, templated precision) ----------------
// FIRST:  gather f32 g0, write fp16 g1 = dinv*relu(zW+b)   (halves layer-2 bytes)
// !FIRST: gather fp16 g1 (f32 accumulate), write f32 h2 = relu(zW+b)

template<bool FIRST>
__launch_bounds__(256, 8)
__global__ void k_fused(const void* __restrict__ gvp, const int* __restrict__ rp,
                        const int* __restrict__ cs, const float* __restrict__ dinv,
                        const float* __restrict__ W, const float* __restrict__ bias,
                        void* __restrict__ outp, int n){
  __shared__ float zs[32][132];
  int t = threadIdx.x;
  int grp = t>>5, lane = t&31;
  int node0 = blockIdx.x*32;
  int c4 = lane*4;
  const float*  gf = (const float*)gvp;
  const __half* gh = (const __half*)gvp;
  // ---- phase 1: gather (group-private rows zs[grp*4 .. grp*4+3]) ----
  for(int nn=0; nn<4; nn++){
    int node = node0 + grp*4 + nn;
    if(node<n){
      float4 acc, acc2 = make_float4(0.f,0.f,0.f,0.f);
      if constexpr(FIRST){
        acc = *(const float4*)(gf + (size_t)node*DF + c4);
      } else {
        h2x2 v = *(const h2x2*)(gh + (size_t)node*DF + c4);
        float2 lo = __half22float2(v.a), hi = __half22float2(v.b);
        acc = make_float4(lo.x, lo.y, hi.x, hi.y);
      }
      int e0=rp[node], e1=rp[node+1];
      int e=e0;
      for(; e+1<e1; e+=2){
        int s0=cs[e], s1=cs[e+1];
        if constexpr(FIRST){
          float4 v0 = *(const float4*)(gf + (size_t)s0*DF + c4);
          float4 v1 = *(const float4*)(gf + (size_t)s1*DF + c4);
          acc.x+=v0.x;  acc.y+=v0.y;  acc.z+=v0.z;  acc.w+=v0.w;
          acc2.x+=v1.x; acc2.y+=v1.y; acc2.z+=v1.z; acc2.w+=v1.w;
        } else {
          h2x2 u0 = *(const h2x2*)(gh + (size_t)s0*DF + c4);
          h2x2 u1 = *(const h2x2*)(gh + (size_t)s1*DF + c4);
          float2 a0=__half22float2(u0.a), b0=__half22float2(u0.b);
          float2 a1=__half22float2(u1.a), b1=__half22float2(u1.b);
          acc.x+=a0.x;  acc.y+=a0.y;  acc.z+=b0.x;  acc.w+=b0.y;
          acc2.x+=a1.x; acc2.y+=a1.y; acc2.z+=b1.x; acc2.w+=b1.y;
        }
      }
      if(e<e1){
        int s0=cs[e];
        if constexpr(FIRST){
          float4 v0=*(const float4*)(gf + (size_t)s0*DF + c4);
          acc.x+=v0.x; acc.y+=v0.y; acc.z+=v0.z; acc.w+=v0.w;
        } else {
          h2x2 u0 = *(const h2x2*)(gh + (size_t)s0*DF + c4);
          float2 a0=__half22float2(u0.a), b0=__half22float2(u0.b);
          acc.x+=a0.x; acc.y+=a0.y; acc.z+=b0.x; acc.w+=b0.y;
        }
      }
      float dv = dinv[node];
      float4 zv;
      zv.x = dv*(acc.x+acc2.x);
      zv.y = dv*(acc.y+acc2.y);
      zv.z = dv*(acc.z+acc2.z);
      zv.w = dv*(acc.w+acc2.w);
      *(float4*)&zs[grp*4+nn][c4] = zv;
    }
  }
  // wave-local LDS sync: rows are written and read by the same wave.
  asm volatile("s_waitcnt lgkmcnt(0)" ::: "memory");
  __builtin_amdgcn_wave_barrier();
  __builtin_amdgcn_sched_barrier(0);
  // ---- phase 2: y = z @ W + b ----
  const float4* Wr = (const float4*)W;      // [128][32] float4 view
  int r0 = grp*4;
  float4 a0 = make_float4(0.f,0.f,0.f,0.f);
  float4 a1 = a0, a2 = a0, a3 = a0;
  for(int k=0;k<128;k+=4){
    float4 s0 = *(const float4*)&zs[r0  ][k];
    float4 s1 = *(const float4*)&zs[r0+1][k];
    float4 s2 = *(const float4*)&zs[r0+2][k];
    float4 s3 = *(const float4*)&zs[r0+3][k];
#define STEP(KK, C) { float4 w = Wr[(k+KK)*32 + lane];                     \
    a0.x = fmaf(s0.C, w.x, a0.x); a0.y = fmaf(s0.C, w.y, a0.y);            \
    a0.z = fmaf(s0.C, w.z, a0.z); a0.w = fmaf(s0.C, w.w, a0.w);            \
    a1.x = fmaf(s1.C, w.x, a1.x); a1.y = fmaf(s1.C, w.y, a1.y);            \
    a1.z = fmaf(s1.C, w.z, a1.z); a1.w = fmaf(s1.C, w.w, a1.w);            \
    a2.x = fmaf(s2.C, w.x, a2.x); a2.y = fmaf(s2.C, w.y, a2.y);            \
    a2.z = fmaf(s2.C, w.z, a2.z); a2.w = fmaf(s2.C, w.w, a2.w);            \
    a3.x = fmaf(s3.C, w.x, a3.x); a3.y = fmaf(s3.C, w.y, a3.y);            \
    a3.z = fmaf(s3.C, w.z, a3.z); a3.w = fmaf(s3.C, w.w, a3.w); }
    STEP(0, x) STEP(1, y) STEP(2, z) STEP(3, w)
#undef STEP
  }
  float4 bz = ((const float4*)bias)[lane];
  float4 av[4] = {a0, a1, a2, a3};
  for(int nn=0; nn<4; nn++){
    int node = node0 + r0 + nn;
    if(node<n){
      float4 y = av[nn];
      y.x += bz.x; y.y += bz.y; y.z += bz.z; y.w += bz.w;
      y.x = fmaxf(y.x, 0.f); y.y = fmaxf(y.y, 0.f);
      y.z = fmaxf(y.z, 0.f); y.w = fmaxf(y.w, 0.f);
      if constexpr(FIRST){
        float dv = dinv[node];
        y.x*=dv; y.y*=dv; y.z*=dv; y.w*=dv;
        h2x2 st;
        st.a = __floats2half2_rn(y.x, y.y);
        st.b = __floats2half2_rn(y.z, y.w);
        *(h2x2*)((__half*)outp + (size_t)node*DF + c4) = st;
      } else {
        *(float4*)((float*)outp + (size_t)node*DF + c4) = y;
      }
    }
  }
}

// ---------------- Final layer: 128 -> 5 ----------------

__launch_bounds__(256)
__global__ void k_gemm5(const float* __restrict__ X, const float* __restrict__ W2,
                        const float* __restrict__ dinv, float* __restrict__ out, int n){
  __shared__ float xs[32][129];
  __shared__ float wsh[640];
  int t=threadIdx.x;
  int row0=blockIdx.x*32;
  for(int idx=t; idx<640; idx+=256) wsh[idx]=W2[idx];
  for(int idx=t; idx<1024; idx+=256){
    int r=idx>>5, k4=(idx&31)*4;
    int gr=row0+r;
    float4 v = (gr<n)? *(const float4*)(X+(size_t)gr*DF+k4) : make_float4(0.f,0.f,0.f,0.f);
    xs[r][k4]=v.x; xs[r][k4+1]=v.y; xs[r][k4+2]=v.z; xs[r][k4+3]=v.w;
  }
  __syncthreads();
  int r=t>>3, c=t&7;
  int gr=row0+r;
  if(c<5 && gr<n){
    float acc=0.f;
    #pragma unroll
    for(int k=0;k<128;k++) acc = fmaf(xs[r][k], wsh[k*5+c], acc);
    out[(size_t)gr*5+c] = dinv[gr]*acc;
  }
}

__global__ void k_agg5(const float* __restrict__ ht, const int* __restrict__ rp,
                       const int* __restrict__ cs, const float* __restrict__ dinv,
                       const float* __restrict__ b2, float* __restrict__ out, int n){
  int idx = blockIdx.x*256+threadIdx.x;
  int node = idx>>3, c = idx&7;
  if(node>=n || c>=5) return;
  float acc = ht[(size_t)node*5+c];
  int e0=rp[node], e1=rp[node+1];
  for(int e=e0;e<e1;e++){
    acc += ht[(size_t)cs[e]*5+c];
  }
  out[(size_t)node*5+c] = fmaf(dinv[node], acc, b2[c]);
}

// ---------------- launch ----------------

extern "C" void kernel_launch(void* const* d_in, const int* in_sizes, int n_in,
                              void* d_out, int out_size, void* d_ws, size_t ws_size,
                              hipStream_t stream){
  const float* x  = (const float*)d_in[0];
  const int*   ei = (const int*)  d_in[1];
  const float* W0 = (const float*)d_in[2];
  const float* b0 = (const float*)d_in[3];
  const float* W1 = (const float*)d_in[4];
  const float* b1 = (const float*)d_in[5];
  const float* W2 = (const float*)d_in[6];
  const float* b2 = (const float*)d_in[7];
  int n = in_sizes[0]/DF;
  int e = in_sizes[1]/2;
  const int* srcp = ei;
  const int* dstp = ei + e;

  char* ws = (char*)d_ws;
  size_t off=0;
  auto take=[&](size_t bytes)->char*{
    char* p = ws+off;
    off = (off+bytes+511)&~(size_t)511;
    return p;
  };
  int*   bcnt = (int*)  take((size_t)NB_MAX*4);
  int*   bbase= (int*)  take((size_t)(NB_MAX+1)*4);
  int*   bcur = (int*)  take((size_t)NB_MAX*4);
  int*   rp   = (int*)  take((size_t)(n+1)*4);
  int*   csr  = (int*)  take((size_t)e*4);
  float* dinv = (float*)take((size_t)n*4);
  float* bufA = (float*)take((size_t)n*DF*4);
  float* bufB = (float*)take((size_t)n*DF*4);
  int2*  binned = (int2*)bufB;   // dead before first write of bufB

  hipMemsetAsync(bcnt, 0, (size_t)NB_MAX*4, stream);

  int nb   = (n + RB-1) >> RB_SHIFT;
  int ncb  = (e + CHUNK-1) / CHUNK;
  k_bhist     <<<ncb, 256, 0, stream>>>(dstp, bcnt, e);
  k_bscan     <<<1,   256, 0, stream>>>(bcnt, bbase, bcur, e);
  k_binscatter<<<ncb, 256, 0, stream>>>(srcp, dstp, bcur, binned, e);
  k_localcsr  <<<nb,  256, 0, stream>>>(binned, bbase, rp, csr, dinv, n, e);

  int nfb = (n+31)/32;
  k_prescale<<<(n*(DF/4)+255)/256, 256, 0, stream>>>(x, dinv, bufA, n);
  // layer 1: gather f32 g0(bufA) -> bufB = fp16 g1 = dinv*relu(y)
  k_fused<true>  <<<nfb, 256, 0, stream>>>(bufA, rp, csr, dinv, W0, b0, bufB, n);
  // layer 2: gather fp16 g1(bufB) -> bufA = f32 h2 = relu(y)
  k_fused<false> <<<nfb, 256, 0, stream>>>(bufB, rp, csr, dinv, W1, b1, bufA, n);
  // layer 3: ht = dinv*(h2 @ W2) in bufB, then aggregate
  k_gemm5   <<<(n+31)/32, 256, 0, stream>>>(bufA, W2, dinv, (float*)bufB, n);
  k_agg5    <<<((n*8)+255)/256, 256, 0, stream>>>((float*)bufB, rp, csr, dinv, b2, (float*)d_out, n);
}

// Round 13
// 415.454 us; speedup vs baseline: 1.7712x; 1.0202x over previous
//
#include <hip/hip_runtime.h>
#include <hip/hip_fp16.h>

#define DF 128
#define RB 512            // nodes per bucket (power of two)
#define RB_SHIFT 9
#define NB_MAX 256        // supports n <= 131072
#define CHUNK 8192        // edges per binning block

struct h2x2 { __half2 a, b; };   // 8 bytes = 4 halves

// ---------------- CSR build (bucketed, coalesced) ----------------

__global__ void k_bhist(const int* __restrict__ dst, int* __restrict__ bcnt, int e){
  __shared__ int h[NB_MAX];
  int t = threadIdx.x;
  h[t] = 0;
  __syncthreads();
  int base = blockIdx.x*CHUNK;
  for(int k=0;k<CHUNK/256;k++){
    int i = base + t + k*256;
    if(i<e) atomicAdd(&h[dst[i]>>RB_SHIFT], 1);
  }
  __syncthreads();
  if(h[t]) atomicAdd(&bcnt[t], h[t]);
}

__global__ void k_bscan(const int* __restrict__ bcnt, int* __restrict__ bbase,
                        int* __restrict__ bcur, int e){
  __shared__ int sh[NB_MAX];
  int t = threadIdx.x;
  int c = bcnt[t];
  sh[t] = c;
  __syncthreads();
  for(int off=1; off<256; off<<=1){
    int v = (t>=off)? sh[t-off]:0;
    __syncthreads();
    sh[t]+=v;
    __syncthreads();
  }
  int excl = sh[t]-c;
  bbase[t]=excl; bcur[t]=excl;
  if(t==255) bbase[256]=sh[255];   // == e
}

__launch_bounds__(256)
__global__ void k_binscatter(const int* __restrict__ src, const int* __restrict__ dst,
                             int* __restrict__ bcur, int2* __restrict__ binned, int e){
  __shared__ int h[NB_MAX];
  __shared__ int lexcl[NB_MAX];
  __shared__ int lcur[NB_MAX];
  __shared__ int gbase[NB_MAX];
  __shared__ int2 pairs[CHUNK];
  int t = threadIdx.x;
  int c0 = blockIdx.x*CHUNK;
  int cc = min(CHUNK, e - c0);
  h[t]=0;
  __syncthreads();
  for(int k=0;k<CHUNK/256;k++){
    int i = t + k*256;
    if(i<cc) atomicAdd(&h[dst[c0+i]>>RB_SHIFT], 1);
  }
  __syncthreads();
  int hc = h[t];
  lexcl[t]=hc;
  __syncthreads();
  for(int off=1; off<256; off<<=1){
    int v = (t>=off)? lexcl[t-off]:0;
    __syncthreads();
    lexcl[t]+=v;
    __syncthreads();
  }
  int incl = lexcl[t];
  lexcl[t] = incl - hc;
  lcur[t]  = incl - hc;
  gbase[t] = hc ? atomicAdd(&bcur[t], hc) : 0;
  __syncthreads();
  for(int k=0;k<CHUNK/256;k++){
    int i = t + k*256;
    if(i<cc){
      int d = dst[c0+i], s = src[c0+i];
      int lp = atomicAdd(&lcur[d>>RB_SHIFT], 1);
      pairs[lp] = make_int2(d, s);
    }
  }
  __syncthreads();
  for(int k=0;k<CHUNK/256;k++){
    int p = t + k*256;
    if(p<cc){
      int2 pr = pairs[p];
      int b = pr.x>>RB_SHIFT;
      binned[gbase[b] + (p - lexcl[b])] = pr;
    }
  }
}

__launch_bounds__(256)
__global__ void k_localcsr(const int2* __restrict__ binned, const int* __restrict__ bbase,
                           int* __restrict__ rp, int* __restrict__ csr,
                           float* __restrict__ dinv, int n, int e){
  __shared__ int cnt[RB];
  __shared__ int sh[256];
  __shared__ int cur[RB];
  int b = blockIdx.x, t = threadIdx.x;
  int node0 = b<<RB_SHIFT;
  int e0 = bbase[b], e1 = bbase[b+1];
  cnt[t]=0; cnt[t+256]=0;
  __syncthreads();
  for(int i=e0+t; i<e1; i+=256)
    atomicAdd(&cnt[binned[i].x - node0], 1);
  __syncthreads();
  int c0 = cnt[2*t], c1 = cnt[2*t+1];
  int s = c0+c1;
  sh[t]=s;
  __syncthreads();
  for(int off=1; off<256; off<<=1){
    int v = (t>=off)? sh[t-off]:0;
    __syncthreads();
    sh[t]+=v;
    __syncthreads();
  }
  int excl = sh[t]-s;
  int g0 = node0+2*t, g1 = node0+2*t+1;
  if(g0<n){ rp[g0]=e0+excl;    dinv[g0]=rsqrtf((float)(c0+1)); }
  if(g1<n){ rp[g1]=e0+excl+c0; dinv[g1]=rsqrtf((float)(c1+1)); }
  cur[2*t]=excl; cur[2*t+1]=excl+c0;
  if(b==0 && t==0) rp[n]=e;
  __syncthreads();
  for(int i=e0+t; i<e1; i+=256){
    int2 pr = binned[i];
    int lp = atomicAdd(&cur[pr.x - node0], 1);
    csr[e0+lp] = pr.y;
  }
}

// ---------------- GEMM: ht = dinv .* (X @ W) -> fp16, D=128 -> 128 ----------------
// 64x64 tile per block (blockIdx.y selects col half), 256 threads, 4x4/thread.

template<bool IN_HALF>
__launch_bounds__(256)
__global__ void k_gemm128h(const void* __restrict__ Xp, const float* __restrict__ W,
                           const float* __restrict__ dinv, __half* __restrict__ out, int n){
  __shared__ float xs[64][132];
  __shared__ float wt[64][132];
  int row0 = blockIdx.x*64;
  int c0g  = blockIdx.y*64;
  int t = threadIdx.x;
  for(int idx=t; idx<64*128; idx+=256){
    int k = idx>>6, c = idx&63;
    wt[c][k] = W[k*DF + c0g + c];
  }
  for(int idx=t; idx<64*32; idx+=256){
    int r = idx>>5, k4=(idx&31)*4;
    int gr = row0+r;
    float4 v = make_float4(0.f,0.f,0.f,0.f);
    if(gr<n){
      if constexpr(IN_HALF){
        h2x2 u = *(const h2x2*)((const __half*)Xp + (size_t)gr*DF + k4);
        float2 a=__half22float2(u.a), b=__half22float2(u.b);
        v = make_float4(a.x,a.y,b.x,b.y);
      } else {
        v = *(const float4*)((const float*)Xp + (size_t)gr*DF + k4);
      }
    }
    xs[r][k4]=v.x; xs[r][k4+1]=v.y; xs[r][k4+2]=v.z; xs[r][k4+3]=v.w;
  }
  __syncthreads();
  int tr=t>>4, tc=t&15;
  int r0=tr*4;
  float acc[4][4]={};
  for(int k=0;k<128;k+=4){
    float4 a0=*(const float4*)&xs[r0  ][k];
    float4 a1=*(const float4*)&xs[r0+1][k];
    float4 a2=*(const float4*)&xs[r0+2][k];
    float4 a3=*(const float4*)&xs[r0+3][k];
    float4 b0=*(const float4*)&wt[tc   ][k];
    float4 b1=*(const float4*)&wt[tc+16][k];
    float4 b2=*(const float4*)&wt[tc+32][k];
    float4 b3=*(const float4*)&wt[tc+48][k];
#define DOT(ACC,A,B) ACC = fmaf(A.x,B.x, fmaf(A.y,B.y, fmaf(A.z,B.z, fmaf(A.w,B.w, ACC))))
    DOT(acc[0][0],a0,b0); DOT(acc[0][1],a0,b1); DOT(acc[0][2],a0,b2); DOT(acc[0][3],a0,b3);
    DOT(acc[1][0],a1,b0); DOT(acc[1][1],a1,b1); DOT(acc[1][2],a1,b2); DOT(acc[1][3],a1,b3);
    DOT(acc[2][0],a2,b0); DOT(acc[2][1],a2,b1); DOT(acc[2][2],a2,b2); DOT(acc[2][3],a2,b3);
    DOT(acc[3][0],a3,b0); DOT(acc[3][1],a3,b1); DOT(acc[3][2],a3,b2); DOT(acc[3][3],a3,b3);
#undef DOT
  }
  for(int i=0;i<4;i++){
    int gr=row0+r0+i;
    if(gr<n){
      float dv=dinv[gr];
      __half* ob = out + (size_t)gr*DF + c0g + tc;
      ob[0]  = __float2half(dv*acc[i][0]);
      ob[16] = __float2half(dv*acc[i][1]);
      ob[32] = __float2half(dv*acc[i][2]);
      ob[48] = __float2half(dv*acc[i][3]);
    }
  }
}

// ---------------- Aggregate (fp16 gather): o = relu(dinv*(self+sum)+b) ----------------
// 32 lanes (h2x2 = 4 halves each) per node, 8 nodes per 256-block. Pure gather,
// full load duty-cycle (no GEMM phase) -> proven 3.8 TB/s class access pattern.

template<bool OUT_F32>
__launch_bounds__(256)
__global__ void k_agg128h(const __half* __restrict__ ht, const int* __restrict__ rp,
                          const int* __restrict__ cs, const float* __restrict__ dinv,
                          const float* __restrict__ bias, void* __restrict__ outp, int n){
  int t=threadIdx.x;
  int node = blockIdx.x*8 + (t>>5);
  if(node>=n) return;
  int c4 = (t&31)*4;
  h2x2 sv = *(const h2x2*)(ht + (size_t)node*DF + c4);   // self
  float2 sa=__half22float2(sv.a), sb=__half22float2(sv.b);
  float4 acc  = make_float4(sa.x, sa.y, sb.x, sb.y);
  float4 acc2 = make_float4(0.f,0.f,0.f,0.f);
  int e0=rp[node], e1=rp[node+1];
  int e=e0;
  for(; e+1<e1; e+=2){
    int s0=cs[e], s1=cs[e+1];
    h2x2 u0 = *(const h2x2*)(ht + (size_t)s0*DF + c4);
    h2x2 u1 = *(const h2x2*)(ht + (size_t)s1*DF + c4);
    float2 a0=__half22float2(u0.a), b0=__half22float2(u0.b);
    float2 a1=__half22float2(u1.a), b1=__half22float2(u1.b);
    acc.x+=a0.x;  acc.y+=a0.y;  acc.z+=b0.x;  acc.w+=b0.y;
    acc2.x+=a1.x; acc2.y+=a1.y; acc2.z+=b1.x; acc2.w+=b1.y;
  }
  if(e<e1){
    int s0=cs[e];
    h2x2 u0 = *(const h2x2*)(ht + (size_t)s0*DF + c4);
    float2 a0=__half22float2(u0.a), b0=__half22float2(u0.b);
    acc.x+=a0.x; acc.y+=a0.y; acc.z+=b0.x; acc.w+=b0.y;
  }
  acc.x+=acc2.x; acc.y+=acc2.y; acc.z+=acc2.z; acc.w+=acc2.w;
  float dv=dinv[node];
  const float4 bz = *(const float4*)(bias + c4);
  float4 o;
  o.x = fmaxf(fmaf(dv, acc.x, bz.x), 0.f);
  o.y = fmaxf(fmaf(dv, acc.y, bz.y), 0.f);
  o.z = fmaxf(fmaf(dv, acc.z, bz.z), 0.f);
  o.w = fmaxf(fmaf(dv, acc.w, bz.w), 0.f);
  if constexpr(OUT_F32){
    *(float4*)((float*)outp + (size_t)node*DF + c4) = o;
  } else {
    h2x2 st;
    st.a = __floats2half2_rn(o.x, o.y);
    st.b = __floats2half2_rn(o.z, o.w);
    *(h2x2*)((__half*)outp + (size_t)node*DF + c4) = st;
  }
}

// ---------------- Final layer: 128 -> 5 ----------------

__launch_bounds__(256)
__global__ void k_gemm5(const float* __restrict__ X, const float* __restrict__ W2,
                        const float* __restrict__ dinv, float* __restrict__ out, int n){
  __shared__ float xs[32][129];
  __shared__ float wsh[640];
  int t=threadIdx.x;
  int row0=blockIdx.x*32;
  for(int idx=t; idx<640; idx+=256) wsh[idx]=W2[idx];
  for(int idx=t; idx<1024; idx+=256){
    int r=idx>>5, k4=(idx&31)*4;
    int gr=row0+r;
    float4 v = (gr<n)? *(const float4*)(X+(size_t)gr*DF+k4) : make_float4(0.f,0.f,0.f,0.f);
    xs[r][k4]=v.x; xs[r][k4+1]=v.y; xs[r][k4+2]=v.z; xs[r][k4+3]=v.w;
  }
  __syncthreads();
  int r=t>>3, c=t&7;
  int gr=row0+r;
  if(c<5 && gr<n){
    float acc=0.f;
    #pragma unroll
    for(int k=0;k<128;k++) acc = fmaf(xs[r][k], wsh[k*5+c], acc);
    out[(size_t)gr*5+c] = dinv[gr]*acc;
  }
}

__global__ void k_agg5(const float* __restrict__ ht, const int* __restrict__ rp,
                       const int* __restrict__ cs, const float* __restrict__ dinv,
                       const float* __restrict__ b2, float* __restrict__ out, int n){
  int idx = blockIdx.x*256+threadIdx.x;
  int node = idx>>3, c = idx&7;
  if(node>=n || c>=5) return;
  float acc = ht[(size_t)node*5+c];
  int e0=rp[node], e1=rp[node+1];
  for(int e=e0;e<e1;e++){
    acc += ht[(size_t)cs[e]*5+c];
  }
  out[(size_t)node*5+c] = fmaf(dinv[node], acc, b2[c]);
}

// ---------------- launch ----------------

extern "C" void kernel_launch(void* const* d_in, const int* in_sizes, int n_in,
                              void* d_out, int out_size, void* d_ws, size_t ws_size,
                              hipStream_t stream){
  const float* x  = (const float*)d_in[0];
  const int*   ei = (const int*)  d_in[1];
  const float* W0 = (const float*)d_in[2];
  const float* b0 = (const float*)d_in[3];
  const float* W1 = (const float*)d_in[4];
  const float* b1 = (const float*)d_in[5];
  const float* W2 = (const float*)d_in[6];
  const float* b2 = (const float*)d_in[7];
  int n = in_sizes[0]/DF;
  int e = in_sizes[1]/2;
  const int* srcp = ei;
  const int* dstp = ei + e;

  char* ws = (char*)d_ws;
  size_t off=0;
  auto take=[&](size_t bytes)->char*{
    char* p = ws+off;
    off = (off+bytes+511)&~(size_t)511;
    return p;
  };
  int*   bcnt = (int*)  take((size_t)NB_MAX*4);
  int*   bbase= (int*)  take((size_t)(NB_MAX+1)*4);
  int*   bcur = (int*)  take((size_t)NB_MAX*4);
  int*   rp   = (int*)  take((size_t)(n+1)*4);
  int*   csr  = (int*)  take((size_t)e*4);
  float* dinv = (float*)take((size_t)n*4);
  char*  bufA = take((size_t)n*DF*4);
  char*  bufB = take((size_t)n*DF*4);
  int2*  binned = (int2*)bufB;          // dead before first layer write of bufB
  __half* htH  = (__half*)bufA;         // per-layer dinv*(X@W), fp16
  __half* h1H  = (__half*)bufB;         // layer-1 output, fp16
  float*  h2F  = (float*)bufB;          // layer-2 output, f32 (h1 dead by then)
  float*  ht5F = (float*)bufA;          // layer-3 pre-agg, f32

  hipMemsetAsync(bcnt, 0, (size_t)NB_MAX*4, stream);

  int nb   = (n + RB-1) >> RB_SHIFT;
  int ncb  = (e + CHUNK-1) / CHUNK;
  k_bhist     <<<ncb, 256, 0, stream>>>(dstp, bcnt, e);
  k_bscan     <<<1,   256, 0, stream>>>(bcnt, bbase, bcur, e);
  k_binscatter<<<ncb, 256, 0, stream>>>(srcp, dstp, bcur, binned, e);
  k_localcsr  <<<nb,  256, 0, stream>>>(binned, bbase, rp, csr, dinv, n, e);

  dim3 gg((n+63)/64, 2);
  int nab = (n+7)/8;
  // layer 1: ht0 = dinv*(x@W0) fp16 ; h1 = relu(dinv*agg(ht0)+b0) fp16
  k_gemm128h<false><<<gg,  256, 0, stream>>>(x,   W0, dinv, htH, n);
  k_agg128h<false> <<<nab, 256, 0, stream>>>(htH, rp, csr, dinv, b0, h1H, n);
  // layer 2: ht1 = dinv*(h1@W1) fp16 ; h2 = relu(dinv*agg(ht1)+b1) f32
  k_gemm128h<true> <<<gg,  256, 0, stream>>>(h1H, W1, dinv, htH, n);
  k_agg128h<true>  <<<nab, 256, 0, stream>>>(htH, rp, csr, dinv, b1, h2F, n);
  // layer 3: ht2 = dinv*(h2@W2) f32 ; out = dinv*agg(ht2)+b2
  k_gemm5   <<<(n+31)/32, 256, 0, stream>>>(h2F, W2, dinv, ht5F, n);
  k_agg5    <<<((n*8)+255)/256, 256, 0, stream>>>(ht5F, rp, csr, dinv, b2, (float*)d_out, n);
}

// Round 14
// 366.784 us; speedup vs baseline: 2.0063x; 1.1327x over previous
//
#include <hip/hip_runtime.h>
#include <hip/hip_fp16.h>

#define DF 128
#define RB 512            // nodes per bucket (power of two)
#define RB_SHIFT 9
#define NB_MAX 256        // supports n <= 131072
#define CHUNK 8192        // edges per binning block

struct h2x2 { __half2 a, b; };       // 8 bytes = 4 halves
struct h2x4 { __half2 a, b, c, d; }; // 16 bytes = 8 halves

// ---------------- CSR build (bucketed, coalesced) ----------------

__global__ void k_bhist(const int* __restrict__ dst, int* __restrict__ bcnt, int e){
  __shared__ int h[NB_MAX];
  int t = threadIdx.x;
  h[t] = 0;
  __syncthreads();
  int base = blockIdx.x*CHUNK;
  for(int k=0;k<CHUNK/256;k++){
    int i = base + t + k*256;
    if(i<e) atomicAdd(&h[dst[i]>>RB_SHIFT], 1);
  }
  __syncthreads();
  if(h[t]) atomicAdd(&bcnt[t], h[t]);
}

__global__ void k_bscan(const int* __restrict__ bcnt, int* __restrict__ bbase,
                        int* __restrict__ bcur, int e){
  __shared__ int sh[NB_MAX];
  int t = threadIdx.x;
  int c = bcnt[t];
  sh[t] = c;
  __syncthreads();
  for(int off=1; off<256; off<<=1){
    int v = (t>=off)? sh[t-off]:0;
    __syncthreads();
    sh[t]+=v;
    __syncthreads();
  }
  int excl = sh[t]-c;
  bbase[t]=excl; bcur[t]=excl;
  if(t==255) bbase[256]=sh[255];   // == e
}

__launch_bounds__(256)
__global__ void k_binscatter(const int* __restrict__ src, const int* __restrict__ dst,
                             int* __restrict__ bcur, int2* __restrict__ binned, int e){
  __shared__ int h[NB_MAX];
  __shared__ int lexcl[NB_MAX];
  __shared__ int lcur[NB_MAX];
  __shared__ int gbase[NB_MAX];
  __shared__ int2 pairs[CHUNK];
  int t = threadIdx.x;
  int c0 = blockIdx.x*CHUNK;
  int cc = min(CHUNK, e - c0);
  h[t]=0;
  __syncthreads();
  for(int k=0;k<CHUNK/256;k++){
    int i = t + k*256;
    if(i<cc) atomicAdd(&h[dst[c0+i]>>RB_SHIFT], 1);
  }
  __syncthreads();
  int hc = h[t];
  lexcl[t]=hc;
  __syncthreads();
  for(int off=1; off<256; off<<=1){
    int v = (t>=off)? lexcl[t-off]:0;
    __syncthreads();
    lexcl[t]+=v;
    __syncthreads();
  }
  int incl = lexcl[t];
  lexcl[t] = incl - hc;
  lcur[t]  = incl - hc;
  gbase[t] = hc ? atomicAdd(&bcur[t], hc) : 0;
  __syncthreads();
  for(int k=0;k<CHUNK/256;k++){
    int i = t + k*256;
    if(i<cc){
      int d = dst[c0+i], s = src[c0+i];
      int lp = atomicAdd(&lcur[d>>RB_SHIFT], 1);
      pairs[lp] = make_int2(d, s);
    }
  }
  __syncthreads();
  for(int k=0;k<CHUNK/256;k++){
    int p = t + k*256;
    if(p<cc){
      int2 pr = pairs[p];
      int b = pr.x>>RB_SHIFT;
      binned[gbase[b] + (p - lexcl[b])] = pr;
    }
  }
}

__launch_bounds__(256)
__global__ void k_localcsr(const int2* __restrict__ binned, const int* __restrict__ bbase,
                           int* __restrict__ rp, int* __restrict__ csr,
                           float* __restrict__ dinv, int n, int e){
  __shared__ int cnt[RB];
  __shared__ int sh[256];
  __shared__ int cur[RB];
  int b = blockIdx.x, t = threadIdx.x;
  int node0 = b<<RB_SHIFT;
  int e0 = bbase[b], e1 = bbase[b+1];
  cnt[t]=0; cnt[t+256]=0;
  __syncthreads();
  for(int i=e0+t; i<e1; i+=256)
    atomicAdd(&cnt[binned[i].x - node0], 1);
  __syncthreads();
  int c0 = cnt[2*t], c1 = cnt[2*t+1];
  int s = c0+c1;
  sh[t]=s;
  __syncthreads();
  for(int off=1; off<256; off<<=1){
    int v = (t>=off)? sh[t-off]:0;
    __syncthreads();
    sh[t]+=v;
    __syncthreads();
  }
  int excl = sh[t]-s;
  int g0 = node0+2*t, g1 = node0+2*t+1;
  if(g0<n){ rp[g0]=e0+excl;    dinv[g0]=rsqrtf((float)(c0+1)); }
  if(g1<n){ rp[g1]=e0+excl+c0; dinv[g1]=rsqrtf((float)(c1+1)); }
  cur[2*t]=excl; cur[2*t+1]=excl+c0;
  if(b==0 && t==0) rp[n]=e;
  __syncthreads();
  for(int i=e0+t; i<e1; i+=256){
    int2 pr = binned[i];
    int lp = atomicAdd(&cur[pr.x - node0], 1);
    csr[e0+lp] = pr.y;
  }
}

// ---------------- W transpose (once per weight): WT[c][k] = W[k][c] ----------------

__global__ void k_transW(const float* __restrict__ W, float* __restrict__ WT){
  int i = blockIdx.x*256 + threadIdx.x;   // 16384 elements
  int k = i>>7, c = i&127;
  WT[(size_t)c*DF + k] = W[(size_t)k*DF + c];
}

// ---------------- GEMM: ht = dinv .* (X @ W) -> fp16, D=128 -> 128 ----------------
// WT staged with float4 reads+writes (conflict-free), replacing scalar 8-way-conflict writes.

template<bool IN_HALF>
__launch_bounds__(256)
__global__ void k_gemm128h(const void* __restrict__ Xp, const float* __restrict__ WT,
                           const float* __restrict__ dinv, __half* __restrict__ out, int n){
  __shared__ float xs[64][132];
  __shared__ float wt[64][132];
  int row0 = blockIdx.x*64;
  int c0g  = blockIdx.y*64;
  int t = threadIdx.x;
  const float4* WT4 = (const float4*)WT;      // [128][32] float4 view
  for(int idx=t; idx<64*32; idx+=256){
    int c = idx>>5, kq = idx&31;
    *(float4*)&wt[c][kq*4] = WT4[(size_t)(c0g+c)*32 + kq];
  }
  for(int idx=t; idx<64*32; idx+=256){
    int r = idx>>5, k4=(idx&31)*4;
    int gr = row0+r;
    float4 v = make_float4(0.f,0.f,0.f,0.f);
    if(gr<n){
      if constexpr(IN_HALF){
        h2x2 u = *(const h2x2*)((const __half*)Xp + (size_t)gr*DF + k4);
        float2 a=__half22float2(u.a), b=__half22float2(u.b);
        v = make_float4(a.x,a.y,b.x,b.y);
      } else {
        v = *(const float4*)((const float*)Xp + (size_t)gr*DF + k4);
      }
    }
    xs[r][k4]=v.x; xs[r][k4+1]=v.y; xs[r][k4+2]=v.z; xs[r][k4+3]=v.w;
  }
  __syncthreads();
  int tr=t>>4, tc=t&15;
  int r0=tr*4;
  float acc[4][4]={};
  for(int k=0;k<128;k+=4){
    float4 a0=*(const float4*)&xs[r0  ][k];
    float4 a1=*(const float4*)&xs[r0+1][k];
    float4 a2=*(const float4*)&xs[r0+2][k];
    float4 a3=*(const float4*)&xs[r0+3][k];
    float4 b0=*(const float4*)&wt[tc   ][k];
    float4 b1=*(const float4*)&wt[tc+16][k];
    float4 b2=*(const float4*)&wt[tc+32][k];
    float4 b3=*(const float4*)&wt[tc+48][k];
#define DOT(ACC,A,B) ACC = fmaf(A.x,B.x, fmaf(A.y,B.y, fmaf(A.z,B.z, fmaf(A.w,B.w, ACC))))
    DOT(acc[0][0],a0,b0); DOT(acc[0][1],a0,b1); DOT(acc[0][2],a0,b2); DOT(acc[0][3],a0,b3);
    DOT(acc[1][0],a1,b0); DOT(acc[1][1],a1,b1); DOT(acc[1][2],a1,b2); DOT(acc[1][3],a1,b3);
    DOT(acc[2][0],a2,b0); DOT(acc[2][1],a2,b1); DOT(acc[2][2],a2,b2); DOT(acc[2][3],a2,b3);
    DOT(acc[3][0],a3,b0); DOT(acc[3][1],a3,b1); DOT(acc[3][2],a3,b2); DOT(acc[3][3],a3,b3);
#undef DOT
  }
  for(int i=0;i<4;i++){
    int gr=row0+r0+i;
    if(gr<n){
      float dv=dinv[gr];
      __half* ob = out + (size_t)gr*DF + c0g + tc;
      ob[0]  = __float2half(dv*acc[i][0]);
      ob[16] = __float2half(dv*acc[i][1]);
      ob[32] = __float2half(dv*acc[i][2]);
      ob[48] = __float2half(dv*acc[i][3]);
    }
  }
}

// ---------------- Aggregate (fp16 gather): o = relu(dinv*(self+sum)+b) ----------------
// 16 lanes x 16B (h2x4) per row, 16 nodes per 256-block, 4 loads in flight
// (2 accumulator sets) -> 4x the bytes-in-flight of the 8B/2-deep version.

template<bool OUT_F32>
__launch_bounds__(256)
__global__ void k_agg128h(const __half* __restrict__ ht, const int* __restrict__ rp,
                          const int* __restrict__ cs, const float* __restrict__ dinv,
                          const float* __restrict__ bias, void* __restrict__ outp, int n){
  int t=threadIdx.x;
  int node = blockIdx.x*16 + (t>>4);
  if(node>=n) return;
  int l8 = (t&15)*8;              // half-index base within the 128-wide row
  h2x4 sv = *(const h2x4*)(ht + (size_t)node*DF + l8);   // self
  float2 P0=__half22float2(sv.a), P1=__half22float2(sv.b),
         P2=__half22float2(sv.c), P3=__half22float2(sv.d);
  float2 Q0=make_float2(0.f,0.f), Q1=Q0, Q2=Q0, Q3=Q0;
  int e0=rp[node], e1=rp[node+1];
  int e=e0;
  for(; e+3<e1; e+=4){
    int s0=cs[e], s1=cs[e+1], s2=cs[e+2], s3=cs[e+3];
    h2x4 u0 = *(const h2x4*)(ht + (size_t)s0*DF + l8);
    h2x4 u1 = *(const h2x4*)(ht + (size_t)s1*DF + l8);
    h2x4 u2 = *(const h2x4*)(ht + (size_t)s2*DF + l8);
    h2x4 u3 = *(const h2x4*)(ht + (size_t)s3*DF + l8);
    float2 f;
    f=__half22float2(u0.a); P0.x+=f.x; P0.y+=f.y;
    f=__half22float2(u0.b); P1.x+=f.x; P1.y+=f.y;
    f=__half22float2(u0.c); P2.x+=f.x; P2.y+=f.y;
    f=__half22float2(u0.d); P3.x+=f.x; P3.y+=f.y;
    f=__half22float2(u1.a); Q0.x+=f.x; Q0.y+=f.y;
    f=__half22float2(u1.b); Q1.x+=f.x; Q1.y+=f.y;
    f=__half22float2(u1.c); Q2.x+=f.x; Q2.y+=f.y;
    f=__half22float2(u1.d); Q3.x+=f.x; Q3.y+=f.y;
    f=__half22float2(u2.a); P0.x+=f.x; P0.y+=f.y;
    f=__half22float2(u2.b); P1.x+=f.x; P1.y+=f.y;
    f=__half22float2(u2.c); P2.x+=f.x; P2.y+=f.y;
    f=__half22float2(u2.d); P3.x+=f.x; P3.y+=f.y;
    f=__half22float2(u3.a); Q0.x+=f.x; Q0.y+=f.y;
    f=__half22float2(u3.b); Q1.x+=f.x; Q1.y+=f.y;
    f=__half22float2(u3.c); Q2.x+=f.x; Q2.y+=f.y;
    f=__half22float2(u3.d); Q3.x+=f.x; Q3.y+=f.y;
  }
  for(; e<e1; e++){
    h2x4 u0 = *(const h2x4*)(ht + (size_t)cs[e]*DF + l8);
    float2 f;
    f=__half22float2(u0.a); P0.x+=f.x; P0.y+=f.y;
    f=__half22float2(u0.b); P1.x+=f.x; P1.y+=f.y;
    f=__half22float2(u0.c); P2.x+=f.x; P2.y+=f.y;
    f=__half22float2(u0.d); P3.x+=f.x; P3.y+=f.y;
  }
  float dv=dinv[node];
  const float4 bz0 = *(const float4*)(bias + l8);
  const float4 bz1 = *(const float4*)(bias + l8 + 4);
  float4 o0, o1;
  o0.x = fmaxf(fmaf(dv, P0.x+Q0.x, bz0.x), 0.f);
  o0.y = fmaxf(fmaf(dv, P0.y+Q0.y, bz0.y), 0.f);
  o0.z = fmaxf(fmaf(dv, P1.x+Q1.x, bz0.z), 0.f);
  o0.w = fmaxf(fmaf(dv, P1.y+Q1.y, bz0.w), 0.f);
  o1.x = fmaxf(fmaf(dv, P2.x+Q2.x, bz1.x), 0.f);
  o1.y = fmaxf(fmaf(dv, P2.y+Q2.y, bz1.y), 0.f);
  o1.z = fmaxf(fmaf(dv, P3.x+Q3.x, bz1.z), 0.f);
  o1.w = fmaxf(fmaf(dv, P3.y+Q3.y, bz1.w), 0.f);
  if constexpr(OUT_F32){
    float* ob = (float*)outp + (size_t)node*DF + l8;
    *(float4*)ob = o0;
    *(float4*)(ob+4) = o1;
  } else {
    h2x4 st;
    st.a = __floats2half2_rn(o0.x, o0.y);
    st.b = __floats2half2_rn(o0.z, o0.w);
    st.c = __floats2half2_rn(o1.x, o1.y);
    st.d = __floats2half2_rn(o1.z, o1.w);
    *(h2x4*)((__half*)outp + (size_t)node*DF + l8) = st;
  }
}

// ---------------- Final layer: 128 -> 5 ----------------

__launch_bounds__(256)
__global__ void k_gemm5(const float* __restrict__ X, const float* __restrict__ W2,
                        const float* __restrict__ dinv, float* __restrict__ out, int n){
  __shared__ float xs[32][129];
  __shared__ float wsh[640];
  int t=threadIdx.x;
  int row0=blockIdx.x*32;
  for(int idx=t; idx<640; idx+=256) wsh[idx]=W2[idx];
  for(int idx=t; idx<1024; idx+=256){
    int r=idx>>5, k4=(idx&31)*4;
    int gr=row0+r;
    float4 v = (gr<n)? *(const float4*)(X+(size_t)gr*DF+k4) : make_float4(0.f,0.f,0.f,0.f);
    xs[r][k4]=v.x; xs[r][k4+1]=v.y; xs[r][k4+2]=v.z; xs[r][k4+3]=v.w;
  }
  __syncthreads();
  int r=t>>3, c=t&7;
  int gr=row0+r;
  if(c<5 && gr<n){
    float acc=0.f;
    #pragma unroll
    for(int k=0;k<128;k++) acc = fmaf(xs[r][k], wsh[k*5+c], acc);
    out[(size_t)gr*5+c] = dinv[gr]*acc;
  }
}

__global__ void k_agg5(const float* __restrict__ ht, const int* __restrict__ rp,
                       const int* __restrict__ cs, const float* __restrict__ dinv,
                       const float* __restrict__ b2, float* __restrict__ out, int n){
  int idx = blockIdx.x*256+threadIdx.x;
  int node = idx>>3, c = idx&7;
  if(node>=n || c>=5) return;
  float acc = ht[(size_t)node*5+c];
  int e0=rp[node], e1=rp[node+1];
  for(int e=e0;e<e1;e++){
    acc += ht[(size_t)cs[e]*5+c];
  }
  out[(size_t)node*5+c] = fmaf(dinv[node], acc, b2[c]);
}

// ---------------- launch ----------------

extern "C" void kernel_launch(void* const* d_in, const int* in_sizes, int n_in,
                              void* d_out, int out_size, void* d_ws, size_t ws_size,
                              hipStream_t stream){
  const float* x  = (const float*)d_in[0];
  const int*   ei = (const int*)  d_in[1];
  const float* W0 = (const float*)d_in[2];
  const float* b0 = (const float*)d_in[3];
  const float* W1 = (const float*)d_in[4];
  const float* b1 = (const float*)d_in[5];
  const float* W2 = (const float*)d_in[6];
  const float* b2 = (const float*)d_in[7];
  int n = in_sizes[0]/DF;
  int e = in_sizes[1]/2;
  const int* srcp = ei;
  const int* dstp = ei + e;

  char* ws = (char*)d_ws;
  size_t off=0;
  auto take=[&](size_t bytes)->char*{
    char* p = ws+off;
    off = (off+bytes+511)&~(size_t)511;
    return p;
  };
  int*   bcnt = (int*)  take((size_t)NB_MAX*4);
  int*   bbase= (int*)  take((size_t)(NB_MAX+1)*4);
  int*   bcur = (int*)  take((size_t)NB_MAX*4);
  int*   rp   = (int*)  take((size_t)(n+1)*4);
  int*   csr  = (int*)  take((size_t)e*4);
  float* dinv = (float*)take((size_t)n*4);
  float* WT0  = (float*)take((size_t)DF*DF*4);
  float* WT1  = (float*)take((size_t)DF*DF*4);
  char*  bufA = take((size_t)n*DF*4);
  char*  bufB = take((size_t)n*DF*4);
  int2*  binned = (int2*)bufB;          // dead before first layer write of bufB
  __half* htH  = (__half*)bufA;         // per-layer dinv*(X@W), fp16
  __half* h1H  = (__half*)bufB;         // layer-1 output, fp16
  float*  h2F  = (float*)bufB;          // layer-2 output, f32 (h1 dead by then)
  float*  ht5F = (float*)bufA;          // layer-3 pre-agg, f32

  hipMemsetAsync(bcnt, 0, (size_t)NB_MAX*4, stream);

  int nb   = (n + RB-1) >> RB_SHIFT;
  int ncb  = (e + CHUNK-1) / CHUNK;
  k_transW    <<<64,  256, 0, stream>>>(W0, WT0);
  k_transW    <<<64,  256, 0, stream>>>(W1, WT1);
  k_bhist     <<<ncb, 256, 0, stream>>>(dstp, bcnt, e);
  k_bscan     <<<1,   256, 0, stream>>>(bcnt, bbase, bcur, e);
  k_binscatter<<<ncb, 256, 0, stream>>>(srcp, dstp, bcur, binned, e);
  k_localcsr  <<<nb,  256, 0, stream>>>(binned, bbase, rp, csr, dinv, n, e);

  dim3 gg((n+63)/64, 2);
  int nab = (n+15)/16;
  // layer 1: ht0 = dinv*(x@W0) fp16 ; h1 = relu(dinv*agg(ht0)+b0) fp16
  k_gemm128h<false><<<gg,  256, 0, stream>>>(x,   WT0, dinv, htH, n);
  k_agg128h<false> <<<nab, 256, 0, stream>>>(htH, rp, csr, dinv, b0, h1H, n);
  // layer 2: ht1 = dinv*(h1@W1) fp16 ; h2 = relu(dinv*agg(ht1)+b1) f32
  k_gemm128h<true> <<<gg,  256, 0, stream>>>(h1H, WT1, dinv, htH, n);
  k_agg128h<true>  <<<nab, 256, 0, stream>>>(htH, rp, csr, dinv, b1, h2F, n);
  // layer 3: ht2 = dinv*(h2@W2) f32 ; out = dinv*agg(ht2)+b2
  k_gemm5   <<<(n+31)/32, 256, 0, stream>>>(h2F, W2, dinv, ht5F, n);
  k_agg5    <<<((n*8)+255)/256, 256, 0, stream>>>(ht5F, rp, csr, dinv, b2, (float*)d_out, n);
}

// Round 15
// 315.340 us; speedup vs baseline: 2.3336x; 1.1631x over previous
//
#include <hip/hip_runtime.h>
#include <hip/hip_fp16.h>

#define DF 128
#define RB 512            // nodes per bucket (power of two)
#define RB_SHIFT 9
#define NB_MAX 256        // supports n <= 131072
#define CHUNK 8192        // edges per binning block

struct h2x2 { __half2 a, b; };       // 8 bytes = 4 halves
struct h2x4 { __half2 a, b, c, d; }; // 16 bytes = 8 halves

typedef _Float16 hh2 __attribute__((ext_vector_type(2)));
struct alignas(16) hv8 { hh2 a, b, c, d; };   // 16 bytes = 8 halves

#if __has_builtin(__builtin_amdgcn_fdot2)
#define FDOT2(A,B,C) __builtin_amdgcn_fdot2((A),(B),(C),false)
#else
__device__ inline float FDOT2(hh2 a, hh2 b, float c){
  return fmaf((float)a.x,(float)b.x, fmaf((float)a.y,(float)b.y, c));
}
#endif

// ---------------- CSR build (bucketed, coalesced) ----------------

__global__ void k_bhist(const int* __restrict__ dst, int* __restrict__ bcnt, int e){
  __shared__ int h[NB_MAX];
  int t = threadIdx.x;
  h[t] = 0;
  __syncthreads();
  int base = blockIdx.x*CHUNK;
  for(int k=0;k<CHUNK/256;k++){
    int i = base + t + k*256;
    if(i<e) atomicAdd(&h[dst[i]>>RB_SHIFT], 1);
  }
  __syncthreads();
  if(h[t]) atomicAdd(&bcnt[t], h[t]);
}

__global__ void k_bscan(const int* __restrict__ bcnt, int* __restrict__ bbase,
                        int* __restrict__ bcur, int e){
  __shared__ int sh[NB_MAX];
  int t = threadIdx.x;
  int c = bcnt[t];
  sh[t] = c;
  __syncthreads();
  for(int off=1; off<256; off<<=1){
    int v = (t>=off)? sh[t-off]:0;
    __syncthreads();
    sh[t]+=v;
    __syncthreads();
  }
  int excl = sh[t]-c;
  bbase[t]=excl; bcur[t]=excl;
  if(t==255) bbase[256]=sh[255];   // == e
}

__launch_bounds__(256)
__global__ void k_binscatter(const int* __restrict__ src, const int* __restrict__ dst,
                             int* __restrict__ bcur, int2* __restrict__ binned, int e){
  __shared__ int h[NB_MAX];
  __shared__ int lexcl[NB_MAX];
  __shared__ int lcur[NB_MAX];
  __shared__ int gbase[NB_MAX];
  __shared__ int2 pairs[CHUNK];
  int t = threadIdx.x;
  int c0 = blockIdx.x*CHUNK;
  int cc = min(CHUNK, e - c0);
  h[t]=0;
  __syncthreads();
  for(int k=0;k<CHUNK/256;k++){
    int i = t + k*256;
    if(i<cc) atomicAdd(&h[dst[c0+i]>>RB_SHIFT], 1);
  }
  __syncthreads();
  int hc = h[t];
  lexcl[t]=hc;
  __syncthreads();
  for(int off=1; off<256; off<<=1){
    int v = (t>=off)? lexcl[t-off]:0;
    __syncthreads();
    lexcl[t]+=v;
    __syncthreads();
  }
  int incl = lexcl[t];
  lexcl[t] = incl - hc;
  lcur[t]  = incl - hc;
  gbase[t] = hc ? atomicAdd(&bcur[t], hc) : 0;
  __syncthreads();
  for(int k=0;k<CHUNK/256;k++){
    int i = t + k*256;
    if(i<cc){
      int d = dst[c0+i], s = src[c0+i];
      int lp = atomicAdd(&lcur[d>>RB_SHIFT], 1);
      pairs[lp] = make_int2(d, s);
    }
  }
  __syncthreads();
  for(int k=0;k<CHUNK/256;k++){
    int p = t + k*256;
    if(p<cc){
      int2 pr = pairs[p];
      int b = pr.x>>RB_SHIFT;
      binned[gbase[b] + (p - lexcl[b])] = pr;
    }
  }
}

__launch_bounds__(256)
__global__ void k_localcsr(const int2* __restrict__ binned, const int* __restrict__ bbase,
                           int* __restrict__ rp, int* __restrict__ csr,
                           float* __restrict__ dinv, int n, int e){
  __shared__ int cnt[RB];
  __shared__ int sh[256];
  __shared__ int cur[RB];
  int b = blockIdx.x, t = threadIdx.x;
  int node0 = b<<RB_SHIFT;
  int e0 = bbase[b], e1 = bbase[b+1];
  cnt[t]=0; cnt[t+256]=0;
  __syncthreads();
  for(int i=e0+t; i<e1; i+=256)
    atomicAdd(&cnt[binned[i].x - node0], 1);
  __syncthreads();
  int c0 = cnt[2*t], c1 = cnt[2*t+1];
  int s = c0+c1;
  sh[t]=s;
  __syncthreads();
  for(int off=1; off<256; off<<=1){
    int v = (t>=off)? sh[t-off]:0;
    __syncthreads();
    sh[t]+=v;
    __syncthreads();
  }
  int excl = sh[t]-s;
  int g0 = node0+2*t, g1 = node0+2*t+1;
  if(g0<n){ rp[g0]=e0+excl;    dinv[g0]=rsqrtf((float)(c0+1)); }
  if(g1<n){ rp[g1]=e0+excl+c0; dinv[g1]=rsqrtf((float)(c1+1)); }
  cur[2*t]=excl; cur[2*t+1]=excl+c0;
  if(b==0 && t==0) rp[n]=e;
  __syncthreads();
  for(int i=e0+t; i<e1; i+=256){
    int2 pr = binned[i];
    int lp = atomicAdd(&cur[pr.x - node0], 1);
    csr[e0+lp] = pr.y;
  }
}

// ---------------- W transpose -> fp16 (once per weight): WTh[c][k] = W[k][c] ----------------

__global__ void k_transW(const float* __restrict__ W, __half* __restrict__ WTh){
  int i = blockIdx.x*256 + threadIdx.x;   // 16384 elements
  int k = i>>7, c = i&127;
  WTh[(size_t)c*DF + k] = __float2half(W[(size_t)k*DF + c]);
}

// ---------------- GEMM: ht = dinv .* (X @ W) -> fp16, fp16 LDS + fdot2 ----------------
// LDS 2x 17.4KB (fp16, pad 136 halves/row) -> 4 blocks/CU. Inner loop: hv8
// (16B) LDS reads + v_dot2_f32_f16 (2 MAC/inst, f32 accumulate).

template<bool IN_HALF>
__launch_bounds__(256)
__global__ void k_gemm128h(const void* __restrict__ Xp, const __half* __restrict__ WTh,
                           const float* __restrict__ dinv, __half* __restrict__ out, int n){
  __shared__ hh2 xsh[64][68];   // 136 halves/row (8-half pad)
  __shared__ hh2 wth[64][68];
  int row0 = blockIdx.x*64;
  int c0g  = blockIdx.y*64;
  int t = threadIdx.x;
  // stage WT half-tile (fp16 global, hv8 loads)
  for(int idx=t; idx<64*16; idx+=256){
    int c = idx>>4, k8 = idx&15;
    *(hv8*)&wth[c][k8*4] = *(const hv8*)(WTh + (size_t)(c0g+c)*DF + k8*8);
  }
  // stage X tile (convert f32->fp16 in-flight for layer 1)
  for(int idx=t; idx<64*16; idx+=256){
    int r = idx>>4, k8 = idx&15;
    int gr = row0+r;
    hv8 u;
    if(gr<n){
      if constexpr(IN_HALF){
        u = *(const hv8*)((const __half*)Xp + (size_t)gr*DF + k8*8);
      } else {
        const float* xp = (const float*)Xp + (size_t)gr*DF + k8*8;
        float4 v0 = *(const float4*)xp;
        float4 v1 = *(const float4*)(xp+4);
        u.a = hh2{(_Float16)v0.x,(_Float16)v0.y};
        u.b = hh2{(_Float16)v0.z,(_Float16)v0.w};
        u.c = hh2{(_Float16)v1.x,(_Float16)v1.y};
        u.d = hh2{(_Float16)v1.z,(_Float16)v1.w};
      }
    } else {
      u.a = hh2{0,0}; u.b = u.a; u.c = u.a; u.d = u.a;
    }
    *(hv8*)&xsh[r][k8*4] = u;
  }
  __syncthreads();
  int tr=t>>4, tc=t&15;
  int r0=tr*4;
  float acc[4][4]={};
  for(int k8=0;k8<16;k8++){      // 8 k-values per step
    hv8 A0 = *(const hv8*)&xsh[r0  ][k8*4];
    hv8 A1 = *(const hv8*)&xsh[r0+1][k8*4];
    hv8 A2 = *(const hv8*)&xsh[r0+2][k8*4];
    hv8 A3 = *(const hv8*)&xsh[r0+3][k8*4];
    hv8 B0 = *(const hv8*)&wth[tc   ][k8*4];
    hv8 B1 = *(const hv8*)&wth[tc+16][k8*4];
    hv8 B2 = *(const hv8*)&wth[tc+32][k8*4];
    hv8 B3 = *(const hv8*)&wth[tc+48][k8*4];
#define DOT8(ACC,A,B) ACC=FDOT2(A.a,B.a,ACC); ACC=FDOT2(A.b,B.b,ACC); \
                      ACC=FDOT2(A.c,B.c,ACC); ACC=FDOT2(A.d,B.d,ACC);
    DOT8(acc[0][0],A0,B0) DOT8(acc[0][1],A0,B1) DOT8(acc[0][2],A0,B2) DOT8(acc[0][3],A0,B3)
    DOT8(acc[1][0],A1,B0) DOT8(acc[1][1],A1,B1) DOT8(acc[1][2],A1,B2) DOT8(acc[1][3],A1,B3)
    DOT8(acc[2][0],A2,B0) DOT8(acc[2][1],A2,B1) DOT8(acc[2][2],A2,B2) DOT8(acc[2][3],A2,B3)
    DOT8(acc[3][0],A3,B0) DOT8(acc[3][1],A3,B1) DOT8(acc[3][2],A3,B2) DOT8(acc[3][3],A3,B3)
#undef DOT8
  }
  for(int i=0;i<4;i++){
    int gr=row0+r0+i;
    if(gr<n){
      float dv=dinv[gr];
      __half* ob = out + (size_t)gr*DF + c0g + tc;
      ob[0]  = __float2half(dv*acc[i][0]);
      ob[16] = __float2half(dv*acc[i][1]);
      ob[32] = __float2half(dv*acc[i][2]);
      ob[48] = __float2half(dv*acc[i][3]);
    }
  }
}

// ---------------- Aggregate (fp16 gather): o = relu(dinv*(self+sum)+b) ----------------
// 16 lanes x 16B (h2x4) per row, 16 nodes per 256-block, 4 loads in flight.

template<bool OUT_F32>
__launch_bounds__(256)
__global__ void k_agg128h(const __half* __restrict__ ht, const int* __restrict__ rp,
                          const int* __restrict__ cs, const float* __restrict__ dinv,
                          const float* __restrict__ bias, void* __restrict__ outp, int n){
  int t=threadIdx.x;
  int node = blockIdx.x*16 + (t>>4);
  if(node>=n) return;
  int l8 = (t&15)*8;              // half-index base within the 128-wide row
  h2x4 sv = *(const h2x4*)(ht + (size_t)node*DF + l8);   // self
  float2 P0=__half22float2(sv.a), P1=__half22float2(sv.b),
         P2=__half22float2(sv.c), P3=__half22float2(sv.d);
  float2 Q0=make_float2(0.f,0.f), Q1=Q0, Q2=Q0, Q3=Q0;
  int e0=rp[node], e1=rp[node+1];
  int e=e0;
  for(; e+3<e1; e+=4){
    int s0=cs[e], s1=cs[e+1], s2=cs[e+2], s3=cs[e+3];
    h2x4 u0 = *(const h2x4*)(ht + (size_t)s0*DF + l8);
    h2x4 u1 = *(const h2x4*)(ht + (size_t)s1*DF + l8);
    h2x4 u2 = *(const h2x4*)(ht + (size_t)s2*DF + l8);
    h2x4 u3 = *(const h2x4*)(ht + (size_t)s3*DF + l8);
    float2 f;
    f=__half22float2(u0.a); P0.x+=f.x; P0.y+=f.y;
    f=__half22float2(u0.b); P1.x+=f.x; P1.y+=f.y;
    f=__half22float2(u0.c); P2.x+=f.x; P2.y+=f.y;
    f=__half22float2(u0.d); P3.x+=f.x; P3.y+=f.y;
    f=__half22float2(u1.a); Q0.x+=f.x; Q0.y+=f.y;
    f=__half22float2(u1.b); Q1.x+=f.x; Q1.y+=f.y;
    f=__half22float2(u1.c); Q2.x+=f.x; Q2.y+=f.y;
    f=__half22float2(u1.d); Q3.x+=f.x; Q3.y+=f.y;
    f=__half22float2(u2.a); P0.x+=f.x; P0.y+=f.y;
    f=__half22float2(u2.b); P1.x+=f.x; P1.y+=f.y;
    f=__half22float2(u2.c); P2.x+=f.x; P2.y+=f.y;
    f=__half22float2(u2.d); P3.x+=f.x; P3.y+=f.y;
    f=__half22float2(u3.a); Q0.x+=f.x; Q0.y+=f.y;
    f=__half22float2(u3.b); Q1.x+=f.x; Q1.y+=f.y;
    f=__half22float2(u3.c); Q2.x+=f.x; Q2.y+=f.y;
    f=__half22float2(u3.d); Q3.x+=f.x; Q3.y+=f.y;
  }
  for(; e<e1; e++){
    h2x4 u0 = *(const h2x4*)(ht + (size_t)cs[e]*DF + l8);
    float2 f;
    f=__half22float2(u0.a); P0.x+=f.x; P0.y+=f.y;
    f=__half22float2(u0.b); P1.x+=f.x; P1.y+=f.y;
    f=__half22float2(u0.c); P2.x+=f.x; P2.y+=f.y;
    f=__half22float2(u0.d); P3.x+=f.x; P3.y+=f.y;
  }
  float dv=dinv[node];
  const float4 bz0 = *(const float4*)(bias + l8);
  const float4 bz1 = *(const float4*)(bias + l8 + 4);
  float4 o0, o1;
  o0.x = fmaxf(fmaf(dv, P0.x+Q0.x, bz0.x), 0.f);
  o0.y = fmaxf(fmaf(dv, P0.y+Q0.y, bz0.y), 0.f);
  o0.z = fmaxf(fmaf(dv, P1.x+Q1.x, bz0.z), 0.f);
  o0.w = fmaxf(fmaf(dv, P1.y+Q1.y, bz0.w), 0.f);
  o1.x = fmaxf(fmaf(dv, P2.x+Q2.x, bz1.x), 0.f);
  o1.y = fmaxf(fmaf(dv, P2.y+Q2.y, bz1.y), 0.f);
  o1.z = fmaxf(fmaf(dv, P3.x+Q3.x, bz1.z), 0.f);
  o1.w = fmaxf(fmaf(dv, P3.y+Q3.y, bz1.w), 0.f);
  if constexpr(OUT_F32){
    float* ob = (float*)outp + (size_t)node*DF + l8;
    *(float4*)ob = o0;
    *(float4*)(ob+4) = o1;
  } else {
    h2x4 st;
    st.a = __floats2half2_rn(o0.x, o0.y);
    st.b = __floats2half2_rn(o0.z, o0.w);
    st.c = __floats2half2_rn(o1.x, o1.y);
    st.d = __floats2half2_rn(o1.z, o1.w);
    *(h2x4*)((__half*)outp + (size_t)node*DF + l8) = st;
  }
}

// ---------------- Final layer: 128 -> 5 ----------------

__launch_bounds__(256)
__global__ void k_gemm5(const float* __restrict__ X, const float* __restrict__ W2,
                        const float* __restrict__ dinv, float* __restrict__ out, int n){
  __shared__ float xs[32][129];
  __shared__ float wsh[640];
  int t=threadIdx.x;
  int row0=blockIdx.x*32;
  for(int idx=t; idx<640; idx+=256) wsh[idx]=W2[idx];
  for(int idx=t; idx<1024; idx+=256){
    int r=idx>>5, k4=(idx&31)*4;
    int gr=row0+r;
    float4 v = (gr<n)? *(const float4*)(X+(size_t)gr*DF+k4) : make_float4(0.f,0.f,0.f,0.f);
    xs[r][k4]=v.x; xs[r][k4+1]=v.y; xs[r][k4+2]=v.z; xs[r][k4+3]=v.w;
  }
  __syncthreads();
  int r=t>>3, c=t&7;
  int gr=row0+r;
  if(c<5 && gr<n){
    float acc=0.f;
    #pragma unroll
    for(int k=0;k<128;k++) acc = fmaf(xs[r][k], wsh[k*5+c], acc);
    out[(size_t)gr*5+c] = dinv[gr]*acc;
  }
}

__global__ void k_agg5(const float* __restrict__ ht, const int* __restrict__ rp,
                       const int* __restrict__ cs, const float* __restrict__ dinv,
                       const float* __restrict__ b2, float* __restrict__ out, int n){
  int idx = blockIdx.x*256+threadIdx.x;
  int node = idx>>3, c = idx&7;
  if(node>=n || c>=5) return;
  float acc = ht[(size_t)node*5+c];
  int e0=rp[node], e1=rp[node+1];
  for(int e=e0;e<e1;e++){
    acc += ht[(size_t)cs[e]*5+c];
  }
  out[(size_t)node*5+c] = fmaf(dinv[node], acc, b2[c]);
}

// ---------------- launch ----------------

extern "C" void kernel_launch(void* const* d_in, const int* in_sizes, int n_in,
                              void* d_out, int out_size, void* d_ws, size_t ws_size,
                              hipStream_t stream){
  const float* x  = (const float*)d_in[0];
  const int*   ei = (const int*)  d_in[1];
  const float* W0 = (const float*)d_in[2];
  const float* b0 = (const float*)d_in[3];
  const float* W1 = (const float*)d_in[4];
  const float* b1 = (const float*)d_in[5];
  const float* W2 = (const float*)d_in[6];
  const float* b2 = (const float*)d_in[7];
  int n = in_sizes[0]/DF;
  int e = in_sizes[1]/2;
  const int* srcp = ei;
  const int* dstp = ei + e;

  char* ws = (char*)d_ws;
  size_t off=0;
  auto take=[&](size_t bytes)->char*{
    char* p = ws+off;
    off = (off+bytes+511)&~(size_t)511;
    return p;
  };
  int*   bcnt = (int*)  take((size_t)NB_MAX*4);
  int*   bbase= (int*)  take((size_t)(NB_MAX+1)*4);
  int*   bcur = (int*)  take((size_t)NB_MAX*4);
  int*   rp   = (int*)  take((size_t)(n+1)*4);
  int*   csr  = (int*)  take((size_t)e*4);
  float* dinv = (float*)take((size_t)n*4);
  __half* WT0h = (__half*)take((size_t)DF*DF*2);
  __half* WT1h = (__half*)take((size_t)DF*DF*2);
  char*  bufA = take((size_t)n*DF*4);
  char*  bufB = take((size_t)n*DF*4);
  int2*  binned = (int2*)bufB;          // dead before first layer write of bufB
  __half* htH  = (__half*)bufA;         // per-layer dinv*(X@W), fp16
  __half* h1H  = (__half*)bufB;         // layer-1 output, fp16
  float*  h2F  = (float*)bufB;          // layer-2 output, f32 (h1 dead by then)
  float*  ht5F = (float*)bufA;          // layer-3 pre-agg, f32

  hipMemsetAsync(bcnt, 0, (size_t)NB_MAX*4, stream);

  int nb   = (n + RB-1) >> RB_SHIFT;
  int ncb  = (e + CHUNK-1) / CHUNK;
  k_transW    <<<64,  256, 0, stream>>>(W0, WT0h);
  k_transW    <<<64,  256, 0, stream>>>(W1, WT1h);
  k_bhist     <<<ncb, 256, 0, stream>>>(dstp, bcnt, e);
  k_bscan     <<<1,   256, 0, stream>>>(bcnt, bbase, bcur, e);
  k_binscatter<<<ncb, 256, 0, stream>>>(srcp, dstp, bcur, binned, e);
  k_localcsr  <<<nb,  256, 0, stream>>>(binned, bbase, rp, csr, dinv, n, e);

  dim3 gg((n+63)/64, 2);
  int nab = (n+15)/16;
  // layer 1: ht0 = dinv*(x@W0) fp16 ; h1 = relu(dinv*agg(ht0)+b0) fp16
  k_gemm128h<false><<<gg,  256, 0, stream>>>(x,   WT0h, dinv, htH, n);
  k_agg128h<false> <<<nab, 256, 0, stream>>>(htH, rp, csr, dinv, b0, h1H, n);
  // layer 2: ht1 = dinv*(h1@W1) fp16 ; h2 = relu(dinv*agg(ht1)+b1) f32
  k_gemm128h<true> <<<gg,  256, 0, stream>>>(h1H, WT1h, dinv, htH, n);
  k_agg128h<true>  <<<nab, 256, 0, stream>>>(htH, rp, csr, dinv, b1, h2F, n);
  // layer 3: ht2 = dinv*(h2@W2) f32 ; out = dinv*agg(ht2)+b2
  k_gemm5   <<<(n+31)/32, 256, 0, stream>>>(h2F, W2, dinv, ht5F, n);
  k_agg5    <<<((n*8)+255)/256, 256, 0, stream>>>(ht5F, rp, csr, dinv, b2, (float*)d_out, n);
}